// Round 4
// baseline (12360.802 us; speedup 1.0000x reference)
//
#include <hip/hip_runtime.h>
#include <hip/hip_bf16.h>

#define NEG_SLOPE 0.2f

__device__ __forceinline__ float b2f(__hip_bfloat16 v) { return __bfloat162float(v); }
__device__ __forceinline__ __hip_bfloat16 f2b(float v) { return __float2bfloat16(v); }

// ---- dtype detection: are float inputs fp32 (flag=1) or bf16 (flag=0)? ----
// Little-endian: for fp32 data, ushort[2k] = LOW mantissa bits of float k ->
// exponent-field bits are uniform garbage (~26% have e==0 or e>=0xC0).
// For genuine bf16 weights ~N(0,0.05^2), every element is well-formed: ~0%.
// Sample EVEN indices (the low halves). 1024 samples -> clean separation.
__global__ void k_detect(const unsigned short* __restrict__ w, int n, int* __restrict__ flag) {
    __shared__ int sh[256];
    int cnt = 0;
    for (int i = threadIdx.x * 2; i < n; i += 512) {   // even indices only
        int e = (w[i] >> 7) & 0xFF;
        if (e == 0 || e >= 0xC0) cnt++;
    }
    sh[threadIdx.x] = cnt;
    __syncthreads();
    for (int off = 128; off >= 1; off >>= 1) {
        if (threadIdx.x < off) sh[threadIdx.x] += sh[threadIdx.x + off];
        __syncthreads();
    }
    if (threadIdx.x == 0) *flag = (sh[0] > 128) ? 1 : 0;
}

// ---- convert a float input (either dtype) into canonical fp32 ----
__global__ void k_cvt(const void* __restrict__ src, float* __restrict__ dst, int n,
                      const int* __restrict__ flag) {
    int i = blockIdx.x * blockDim.x + threadIdx.x;
    if (i >= n) return;
    dst[i] = (*flag) ? ((const float*)src)[i]
                     : b2f(((const __hip_bfloat16*)src)[i]);
}

__device__ __forceinline__ void store_out(void* out, size_t idx, float v, int isF32) {
    if (isF32) ((float*)out)[idx] = v;
    else       ((__hip_bfloat16*)out)[idx] = f2b(v);
}

// ---------------- encoder: h = x @ enc_W + enc_b  ([N,16]@[16,128]) -------
__global__ void k_encoder(const void* __restrict__ x, const float* __restrict__ W,
                          const float* __restrict__ b, const int* __restrict__ flag,
                          __hip_bfloat16* __restrict__ h) {
    int n = blockIdx.x, j = threadIdx.x;
    __shared__ float xs[16];
    if (j < 16)
        xs[j] = (*flag) ? ((const float*)x)[n * 16 + j]
                        : b2f(((const __hip_bfloat16*)x)[n * 16 + j]);
    __syncthreads();
    float acc = b[j];
#pragma unroll
    for (int k = 0; k < 16; ++k) acc += xs[k] * W[k * 128 + j];
    h[(size_t)n * 128 + j] = f2b(acc);
}

// ------------- fused dual GEMM: xl = in@Wl+bl, xr = in@Wr+br --------------
__global__ void k_gemm2(const __hip_bfloat16* __restrict__ in,
                        const float* __restrict__ Wl, const float* __restrict__ bl,
                        const float* __restrict__ Wr, const float* __restrict__ br,
                        __hip_bfloat16* __restrict__ xl, __hip_bfloat16* __restrict__ xr) {
    int n = blockIdx.x, j = threadIdx.x;
    __shared__ float hs[128];
    hs[j] = b2f(in[(size_t)n * 128 + j]);
    __syncthreads();
    float al = bl[j], ar = br[j];
#pragma unroll 4
    for (int k = 0; k < 128; ++k) {
        float hk = hs[k];
        al += hk * Wl[k * 128 + j];
        ar += hk * Wr[k * 128 + j];
    }
    xl[(size_t)n * 128 + j] = f2b(al);
    xr[(size_t)n * 128 + j] = f2b(ar);
}

// ------------- per-layer init: acc=0, denom=0 -----------------------------
__global__ void k_init(float* __restrict__ acc, float* __restrict__ denom, int N) {
    int idx = blockIdx.x * blockDim.x + threadIdx.x;
    if (idx < N * 128) acc[idx] = 0.f;
    if (idx < N * 4) denom[idx] = 0.f;
}

// ------------- edge pass A: one thread per (edge, head): denom += exp(score)
__global__ void k_score(const __hip_bfloat16* __restrict__ xl,
                        const __hip_bfloat16* __restrict__ xr,
                        const int* __restrict__ ei, int E, int N,
                        const float* __restrict__ att,
                        float* __restrict__ den) {
    int idx = blockIdx.x * blockDim.x + threadIdx.x;
    int ET4 = (E + N) * 4;
    if (idx >= ET4) return;
    int e = idx >> 2, h = idx & 3;
    int s, d;
    if (e < E) { s = ei[e]; d = ei[E + e]; } else { s = d = e - E; }
    if ((unsigned)s >= (unsigned)N || (unsigned)d >= (unsigned)N) return;  // defensive
    const __hip_bfloat16* pl = xl + (size_t)s * 128 + h * 32;
    const __hip_bfloat16* pr = xr + (size_t)d * 128 + h * 32;
    const float* pa = att + h * 32;
    float sc = 0.f;
#pragma unroll 8
    for (int c = 0; c < 32; ++c) {
        float v = b2f(pl[c]) + b2f(pr[c]);
        v = (v > 0.f) ? v : NEG_SLOPE * v;
        sc += v * pa[c];
    }
    sc = fminf(fmaxf(sc, -30.f), 30.f);
    atomicAdd(&den[(size_t)d * 4 + h], expf(sc));
}

// ------------- edge pass B: recompute score, alpha, scatter-add -----------
__global__ void k_agg(const __hip_bfloat16* __restrict__ xl,
                      const __hip_bfloat16* __restrict__ xr,
                      const int* __restrict__ ei, int E, int N,
                      const float* __restrict__ att,
                      const float* __restrict__ den,
                      float* __restrict__ acc,
                      void* __restrict__ d_out, size_t aoff, const int* __restrict__ flag) {
    int idx = blockIdx.x * blockDim.x + threadIdx.x;
    int ET4 = (E + N) * 4;
    if (idx >= ET4) return;
    int e = idx >> 2, h = idx & 3;
    int s, d;
    if (e < E) { s = ei[e]; d = ei[E + e]; } else { s = d = e - E; }
    if ((unsigned)s >= (unsigned)N || (unsigned)d >= (unsigned)N) return;  // defensive
    const __hip_bfloat16* pl = xl + (size_t)s * 128 + h * 32;
    const __hip_bfloat16* pr = xr + (size_t)d * 128 + h * 32;
    const float* pa = att + h * 32;
    float sc = 0.f;
#pragma unroll 8
    for (int c = 0; c < 32; ++c) {
        float v = b2f(pl[c]) + b2f(pr[c]);
        v = (v > 0.f) ? v : NEG_SLOPE * v;
        sc += v * pa[c];
    }
    sc = fminf(fmaxf(sc, -30.f), 30.f);
    float dn = fmaxf(den[(size_t)d * 4 + h], 1e-30f);
    float alpha = expf(sc) / dn;
    store_out(d_out, aoff + (size_t)e * 4 + h, alpha, *flag);
    float* pacc = acc + (size_t)d * 128 + h * 32;
#pragma unroll 8
    for (int c = 0; c < 32; ++c) {
        atomicAdd(&pacc[c], b2f(pl[c]) * alpha);
    }
}

// ------------- finalize: hout = (relu?)(acc + bo), bf16 -------------------
__global__ void k_final(const float* __restrict__ acc, const float* __restrict__ bo,
                        __hip_bfloat16* __restrict__ hout, int relu) {
    int n = blockIdx.x, j = threadIdx.x;
    float v = acc[(size_t)n * 128 + j] + bo[j];
    if (relu) v = fmaxf(v, 0.f);
    hout[(size_t)n * 128 + j] = f2b(v);
}

// ------------- MLP head: sigmoid(relu(h2@W1+b1)@W2 + b2) ------------------
__global__ void k_mlp(const __hip_bfloat16* __restrict__ h2,
                      const float* __restrict__ W1, const float* __restrict__ b1,
                      const float* __restrict__ W2, const float* __restrict__ b2,
                      void* __restrict__ d_out, const int* __restrict__ flag) {
    int n = blockIdx.x, j = threadIdx.x;
    __shared__ float hs[128];
    __shared__ float red[128];
    hs[j] = b2f(h2[(size_t)n * 128 + j]);
    __syncthreads();
    float acc = b1[j];
#pragma unroll 4
    for (int k = 0; k < 128; ++k) acc += hs[k] * W1[k * 128 + j];
    red[j] = fmaxf(acc, 0.f) * W2[j];
    __syncthreads();
    for (int off = 64; off >= 1; off >>= 1) {
        if (j < off) red[j] += red[j + off];
        __syncthreads();
    }
    if (j == 0) {
        float s = red[0] + b2[0];
        store_out(d_out, (size_t)n, 1.f / (1.f + expf(-s)), *flag);
    }
}

extern "C" void kernel_launch(void* const* d_in, const int* in_sizes, int n_in,
                              void* d_out, int out_size, void* d_ws, size_t ws_size,
                              hipStream_t stream) {
    const int* ei = (const int*)d_in[1];
    const int N  = in_sizes[0] / 16;
    const int E  = in_sizes[1] / 2;
    const int ET = E + N;

    // ---------------- workspace carve ------------------------------------
    float* P = (float*)d_ws;
    float* encW = P; P += 2048;  float* encb = P; P += 128;
    float* w1l  = P; P += 16384; float* b1l  = P; P += 128;
    float* w1r  = P; P += 16384; float* b1r  = P; P += 128;
    float* att1 = P; P += 128;   float* bo1  = P; P += 128;
    float* w2l  = P; P += 16384; float* b2l  = P; P += 128;
    float* w2r  = P; P += 16384; float* b2r  = P; P += 128;
    float* att2 = P; P += 128;   float* bo2  = P; P += 128;
    float* mW1  = P; P += 16384; float* mb1  = P; P += 128;
    float* mW2  = P; P += 128;   float* mb2  = P; P += 4;
    int*  FLAG  = (int*)P; P += 4;
    float* DEN  = P; P += (size_t)N * 4;                 // N*4 f32
    // 4-region rotation pool (each region N*128 bf16 = 12.8 MB)
    __hip_bfloat16* RA = (__hip_bfloat16*)P;
    __hip_bfloat16* RB = RA + (size_t)N * 128;
    __hip_bfloat16* RC = RB + (size_t)N * 128;
    __hip_bfloat16* RD = RC + (size_t)N * 128;
    float* ACC_AB = (float*)RA;   // spans regions A+B (N*128 f32)
    float* ACC_CD = (float*)RC;   // spans regions C+D (N*128 f32)

    // ---------------- dtype detect + convert params -----------------------
    k_detect<<<1, 256, 0, stream>>>((const unsigned short*)d_in[4], 2048, FLAG);

    struct Cvt { int idx; float* dst; int n; };
    const Cvt cv[] = {
        {4, encW, 2048}, {5, encb, 128},
        {6, w1l, 16384}, {7, b1l, 128}, {8, w1r, 16384}, {9, b1r, 128},
        {10, att1, 128}, {11, bo1, 128},
        {12, w2l, 16384}, {13, b2l, 128}, {14, w2r, 16384}, {15, b2r, 128},
        {16, att2, 128}, {17, bo2, 128},
        {18, mW1, 16384}, {19, mb1, 128}, {20, mW2, 128}, {21, mb2, 1},
    };
    for (const Cvt& c : cv)
        k_cvt<<<(c.n + 255) / 256, 256, 0, stream>>>(d_in[c.idx], c.dst, c.n, FLAG);

    const size_t a1_off = (size_t)N;
    const size_t a2_off = (size_t)N + (size_t)ET * 4;

    const int initGrid = (N * 128 + 255) / 256;
    const int ehGrid   = (ET * 4 + 255) / 256;

    k_encoder<<<N, 128, 0, stream>>>(d_in[0], encW, encb, FLAG, RA);   // h -> A

    // ---- GAT layer 1: h=A, xl=C, xr=D, acc=A+B, h1 -> C ----
    k_gemm2<<<N, 128, 0, stream>>>(RA, w1l, b1l, w1r, b1r, RC, RD);
    k_init<<<initGrid, 256, 0, stream>>>(ACC_AB, DEN, N);
    k_score<<<ehGrid, 256, 0, stream>>>(RC, RD, ei, E, N, att1, DEN);
    k_agg<<<ehGrid, 256, 0, stream>>>(RC, RD, ei, E, N, att1, DEN, ACC_AB, d_out, a1_off, FLAG);
    k_final<<<N, 128, 0, stream>>>(ACC_AB, bo1, RC, 1);                // h1 -> C

    // ---- GAT layer 2: h=C, xl=A, xr=B, acc=C+D, h2 -> A ----
    k_gemm2<<<N, 128, 0, stream>>>(RC, w2l, b2l, w2r, b2r, RA, RB);
    k_init<<<initGrid, 256, 0, stream>>>(ACC_CD, DEN, N);
    k_score<<<ehGrid, 256, 0, stream>>>(RA, RB, ei, E, N, att2, DEN);
    k_agg<<<ehGrid, 256, 0, stream>>>(RA, RB, ei, E, N, att2, DEN, ACC_CD, d_out, a2_off, FLAG);
    k_final<<<N, 128, 0, stream>>>(ACC_CD, bo2, RA, 0);                // h2 -> A

    k_mlp<<<N, 128, 0, stream>>>(RA, mW1, mb1, mW2, mb2, d_out, FLAG);
}

// Round 5
// 1297.863 us; speedup vs baseline: 9.5240x; 9.5240x over previous
//
#include <hip/hip_runtime.h>
#include <hip/hip_bf16.h>

#define NEG_SLOPE 0.2f

__device__ __forceinline__ float b2f(__hip_bfloat16 v) { return __bfloat162float(v); }
__device__ __forceinline__ __hip_bfloat16 f2b(float v) { return __float2bfloat16(v); }
// packed-bf16 unpack: uint holds [lo16 = elem 2k, hi16 = elem 2k+1]
__device__ __forceinline__ float lo16(unsigned u) { return __uint_as_float(u << 16); }
__device__ __forceinline__ float hi16(unsigned u) { return __uint_as_float(u & 0xFFFF0000u); }

// ---- dtype detection (UNCHANGED from round 4 — it works; do not touch) ----
__global__ void k_detect(const unsigned short* __restrict__ w, int n, int* __restrict__ flag) {
    __shared__ int sh[256];
    int cnt = 0;
    for (int i = threadIdx.x * 2; i < n; i += 512) {   // even indices only
        int e = (w[i] >> 7) & 0xFF;
        if (e == 0 || e >= 0xC0) cnt++;
    }
    sh[threadIdx.x] = cnt;
    __syncthreads();
    for (int off = 128; off >= 1; off >>= 1) {
        if (threadIdx.x < off) sh[threadIdx.x] += sh[threadIdx.x + off];
        __syncthreads();
    }
    if (threadIdx.x == 0) *flag = (sh[0] > 128) ? 1 : 0;
}

__global__ void k_cvt(const void* __restrict__ src, float* __restrict__ dst, int n,
                      const int* __restrict__ flag) {
    int i = blockIdx.x * blockDim.x + threadIdx.x;
    if (i >= n) return;
    dst[i] = (*flag) ? ((const float*)src)[i]
                     : b2f(((const __hip_bfloat16*)src)[i]);
}

__device__ __forceinline__ void store_out(void* out, size_t idx, float v, int isF32) {
    if (isF32) ((float*)out)[idx] = v;
    else       ((__hip_bfloat16*)out)[idx] = f2b(v);
}

// ---------------- CSR build (by dst), once per call -----------------------
__global__ void k_zero(int* __restrict__ p, int n) {
    int i = blockIdx.x * blockDim.x + threadIdx.x;
    if (i < n) p[i] = 0;
}

__global__ void k_hist(const int* __restrict__ ei, int E, int N, int* __restrict__ cnt) {
    int e = blockIdx.x * blockDim.x + threadIdx.x;
    if (e >= E + N) return;
    int d = (e < E) ? ei[E + e] : (e - E);
    if ((unsigned)d >= (unsigned)N) return;
    atomicAdd(&cnt[d], 1);
}

// single-block exclusive scan: row_start[0..N], cursor = copy of row_start
__global__ __launch_bounds__(1024) void k_scan(const int* __restrict__ cnt,
                                               int* __restrict__ rs, int* __restrict__ cur, int N) {
    __shared__ int sums[1024];
    const int T = 1024, t = threadIdx.x;
    int chunk = (N + T - 1) / T;
    int beg = t * chunk, end = min(beg + chunk, N);
    int s = 0;
    for (int i = beg; i < end; ++i) s += cnt[i];
    sums[t] = s;
    __syncthreads();
    for (int off = 1; off < T; off <<= 1) {
        int v = (t >= off) ? sums[t - off] : 0;
        __syncthreads();
        sums[t] += v;
        __syncthreads();
    }
    int run = (t == 0) ? 0 : sums[t - 1];
    for (int i = beg; i < end; ++i) { rs[i] = run; cur[i] = run; run += cnt[i]; }
    if (t == T - 1) rs[N] = run;
}

__global__ void k_fill(const int* __restrict__ ei, int E, int N,
                       int* __restrict__ cur, int* __restrict__ eidx) {
    int e = blockIdx.x * blockDim.x + threadIdx.x;
    if (e >= E + N) return;
    int d = (e < E) ? ei[E + e] : (e - E);
    if ((unsigned)d >= (unsigned)N) return;
    int pos = atomicAdd(&cur[d], 1);
    eidx[pos] = e;
}

// ---------------- encoder: h = x @ enc_W + enc_b --------------------------
__global__ void k_encoder(const void* __restrict__ x, const float* __restrict__ W,
                          const float* __restrict__ b, const int* __restrict__ flag,
                          __hip_bfloat16* __restrict__ h) {
    int n = blockIdx.x, j = threadIdx.x;
    __shared__ float xs[16];
    if (j < 16)
        xs[j] = (*flag) ? ((const float*)x)[n * 16 + j]
                        : b2f(((const __hip_bfloat16*)x)[n * 16 + j]);
    __syncthreads();
    float acc = b[j];
#pragma unroll
    for (int k = 0; k < 16; ++k) acc += xs[k] * W[k * 128 + j];
    h[(size_t)n * 128 + j] = f2b(acc);
}

// ---------------- fused dual GEMM: xl = in@Wl+bl, xr = in@Wr+br -----------
__global__ void k_gemm2(const __hip_bfloat16* __restrict__ in,
                        const float* __restrict__ Wl, const float* __restrict__ bl,
                        const float* __restrict__ Wr, const float* __restrict__ br,
                        __hip_bfloat16* __restrict__ xl, __hip_bfloat16* __restrict__ xr) {
    int n = blockIdx.x, j = threadIdx.x;
    __shared__ float hs[128];
    hs[j] = b2f(in[(size_t)n * 128 + j]);
    __syncthreads();
    float al = bl[j], ar = br[j];
#pragma unroll 4
    for (int k = 0; k < 128; ++k) {
        float hk = hs[k];
        al += hk * Wl[k * 128 + j];
        ar += hk * Wr[k * 128 + j];
    }
    xl[(size_t)n * 128 + j] = f2b(al);
    xr[(size_t)n * 128 + j] = f2b(ar);
}

// ---------------- per (edge,head): EX = exp(clamped score) ----------------
__global__ void k_scoreE(const __hip_bfloat16* __restrict__ xl,
                         const __hip_bfloat16* __restrict__ xr,
                         const int* __restrict__ ei, int E, int N,
                         const float* __restrict__ att,
                         float* __restrict__ EX) {
    int idx = blockIdx.x * blockDim.x + threadIdx.x;
    int ET4 = (E + N) * 4;
    if (idx >= ET4) return;
    int e = idx >> 2, h = idx & 3;
    int s, d;
    if (e < E) { s = ei[e]; d = ei[E + e]; } else { s = d = e - E; }
    if ((unsigned)s >= (unsigned)N || (unsigned)d >= (unsigned)N) { EX[idx] = 0.f; return; }
    const uint4* pl = (const uint4*)(xl + (size_t)s * 128 + h * 32);
    const uint4* pr = (const uint4*)(xr + (size_t)d * 128 + h * 32);
    const float* pa = att + h * 32;
    float sc = 0.f;
#pragma unroll
    for (int i = 0; i < 4; ++i) {
        uint4 a = pl[i], b = pr[i];
        const float* aa = pa + i * 8;
        float v0, v1;
        v0 = lo16(a.x) + lo16(b.x); v0 = (v0 > 0.f) ? v0 : NEG_SLOPE * v0;
        v1 = hi16(a.x) + hi16(b.x); v1 = (v1 > 0.f) ? v1 : NEG_SLOPE * v1;
        sc += v0 * aa[0] + v1 * aa[1];
        v0 = lo16(a.y) + lo16(b.y); v0 = (v0 > 0.f) ? v0 : NEG_SLOPE * v0;
        v1 = hi16(a.y) + hi16(b.y); v1 = (v1 > 0.f) ? v1 : NEG_SLOPE * v1;
        sc += v0 * aa[2] + v1 * aa[3];
        v0 = lo16(a.z) + lo16(b.z); v0 = (v0 > 0.f) ? v0 : NEG_SLOPE * v0;
        v1 = hi16(a.z) + hi16(b.z); v1 = (v1 > 0.f) ? v1 : NEG_SLOPE * v1;
        sc += v0 * aa[4] + v1 * aa[5];
        v0 = lo16(a.w) + lo16(b.w); v0 = (v0 > 0.f) ? v0 : NEG_SLOPE * v0;
        v1 = hi16(a.w) + hi16(b.w); v1 = (v1 > 0.f) ? v1 : NEG_SLOPE * v1;
        sc += v0 * aa[6] + v1 * aa[7];
    }
    sc = fminf(fmaxf(sc, -30.f), 30.f);
    EX[idx] = expf(sc);
}

// ---------------- per (node,head): inv_den = 1/sum EX (CSR, no atomics) ---
__global__ void k_den(const float* __restrict__ EX, const int* __restrict__ rs,
                      const int* __restrict__ eidx, int N, int ET,
                      float* __restrict__ inv) {
    int idx = blockIdx.x * blockDim.x + threadIdx.x;
    if (idx >= N * 4) return;
    int n = idx >> 2, h = idx & 3;
    int beg = rs[n], end = rs[n + 1];
    float s = 0.f;
    for (int r = beg; r < end; ++r) {
        int eid = eidx[r];
        if ((unsigned)eid >= (unsigned)ET) continue;
        s += EX[(size_t)eid * 4 + h];
    }
    inv[idx] = 1.f / fmaxf(s, 1e-30f);
}

// ---------------- per (edge,head): alpha -> output tensor -----------------
__global__ void k_alpha(const float* __restrict__ EX, const float* __restrict__ inv,
                        const int* __restrict__ ei, int E, int N,
                        void* __restrict__ d_out, size_t aoff, const int* __restrict__ flag) {
    int idx = blockIdx.x * blockDim.x + threadIdx.x;
    int ET4 = (E + N) * 4;
    if (idx >= ET4) return;
    int e = idx >> 2, h = idx & 3;
    int d = (e < E) ? ei[E + e] : (e - E);
    float a = 0.f;
    if ((unsigned)d < (unsigned)N) a = EX[idx] * inv[(size_t)d * 4 + h];
    store_out(d_out, aoff + idx, a, *flag);
}

// ------- one wave per dst node: hout = (relu?)(sum alpha*xl[src] + bo) ----
__global__ __launch_bounds__(64) void k_aggC(
        const __hip_bfloat16* __restrict__ xl,
        const float* __restrict__ EX, const float* __restrict__ inv,
        const int* __restrict__ rs, const int* __restrict__ eidx,
        const int* __restrict__ ei, int E, int N, int ET,
        const float* __restrict__ bo, int relu,
        __hip_bfloat16* __restrict__ hout) {
    int n = blockIdx.x, lane = threadIdx.x;
    int h = lane >> 4;                      // 2 channels/lane, same head
    float invn = inv[(size_t)n * 4 + h];
    int beg = rs[n], end = rs[n + 1];
    float a0 = 0.f, a1 = 0.f;
    for (int r = beg; r < end; ++r) {
        int eid = eidx[r];
        if ((unsigned)eid >= (unsigned)ET) continue;
        int s = (eid < E) ? ei[eid] : (eid - E);
        if ((unsigned)s >= (unsigned)N) continue;
        float alpha = EX[(size_t)eid * 4 + h] * invn;
        unsigned u = ((const unsigned*)(xl + (size_t)s * 128))[lane];
        a0 += alpha * lo16(u);
        a1 += alpha * hi16(u);
    }
    int c0 = lane * 2;
    float v0 = a0 + bo[c0], v1 = a1 + bo[c0 + 1];
    if (relu) { v0 = fmaxf(v0, 0.f); v1 = fmaxf(v1, 0.f); }
    __hip_bfloat16 h0 = f2b(v0), h1 = f2b(v1);
    ushort2 st;
    st.x = *(unsigned short*)&h0;
    st.y = *(unsigned short*)&h1;
    ((ushort2*)(hout + (size_t)n * 128))[lane] = st;
}

// ---------------- MLP head: sigmoid(relu(h2@W1+b1)@W2 + b2) ---------------
__global__ void k_mlp(const __hip_bfloat16* __restrict__ h2,
                      const float* __restrict__ W1, const float* __restrict__ b1,
                      const float* __restrict__ W2, const float* __restrict__ b2,
                      void* __restrict__ d_out, const int* __restrict__ flag) {
    int n = blockIdx.x, j = threadIdx.x;
    __shared__ float hs[128];
    __shared__ float red[128];
    hs[j] = b2f(h2[(size_t)n * 128 + j]);
    __syncthreads();
    float acc = b1[j];
#pragma unroll 4
    for (int k = 0; k < 128; ++k) acc += hs[k] * W1[k * 128 + j];
    red[j] = fmaxf(acc, 0.f) * W2[j];
    __syncthreads();
    for (int off = 64; off >= 1; off >>= 1) {
        if (j < off) red[j] += red[j + off];
        __syncthreads();
    }
    if (j == 0) {
        float s = red[0] + b2[0];
        store_out(d_out, (size_t)n, 1.f / (1.f + expf(-s)), *flag);
    }
}

extern "C" void kernel_launch(void* const* d_in, const int* in_sizes, int n_in,
                              void* d_out, int out_size, void* d_ws, size_t ws_size,
                              hipStream_t stream) {
    const int* ei = (const int*)d_in[1];
    const int N  = in_sizes[0] / 16;
    const int E  = in_sizes[1] / 2;
    const int ET = E + N;

    // ---------------- workspace carve ------------------------------------
    float* P = (float*)d_ws;
    float* encW = P; P += 2048;  float* encb = P; P += 128;
    float* w1l  = P; P += 16384; float* b1l  = P; P += 128;
    float* w1r  = P; P += 16384; float* b1r  = P; P += 128;
    float* att1 = P; P += 128;   float* bo1  = P; P += 128;
    float* w2l  = P; P += 16384; float* b2l  = P; P += 128;
    float* w2r  = P; P += 16384; float* b2r  = P; P += 128;
    float* att2 = P; P += 128;   float* bo2  = P; P += 128;
    float* mW1  = P; P += 16384; float* mb1  = P; P += 128;
    float* mW2  = P; P += 128;   float* mb2  = P; P += 4;
    int*  FLAG  = (int*)P; P += 4;
    int*  CNT   = (int*)P; P += N;
    int*  RS    = (int*)P; P += N + 1;
    int*  CUR   = (int*)P; P += N;
    int*  EIDX  = (int*)P; P += ET;
    float* EX   = P; P += (size_t)ET * 4;
    float* INV  = P; P += (size_t)N * 4;
    P = (float*)(((uintptr_t)P + 15) & ~(uintptr_t)15);   // 16B-align bf16 regions
    __hip_bfloat16* Hb = (__hip_bfloat16*)P;              // N*128 bf16
    __hip_bfloat16* XL = Hb + (size_t)N * 128;
    __hip_bfloat16* XR = XL + (size_t)N * 128;

    // ---------------- dtype detect + convert params -----------------------
    k_detect<<<1, 256, 0, stream>>>((const unsigned short*)d_in[4], 2048, FLAG);

    struct Cvt { int idx; float* dst; int n; };
    const Cvt cv[] = {
        {4, encW, 2048}, {5, encb, 128},
        {6, w1l, 16384}, {7, b1l, 128}, {8, w1r, 16384}, {9, b1r, 128},
        {10, att1, 128}, {11, bo1, 128},
        {12, w2l, 16384}, {13, b2l, 128}, {14, w2r, 16384}, {15, b2r, 128},
        {16, att2, 128}, {17, bo2, 128},
        {18, mW1, 16384}, {19, mb1, 128}, {20, mW2, 128}, {21, mb2, 1},
    };
    for (const Cvt& c : cv)
        k_cvt<<<(c.n + 255) / 256, 256, 0, stream>>>(d_in[c.idx], c.dst, c.n, FLAG);

    // ---------------- CSR by dst (built once, reused by both layers) ------
    const int etGrid  = (ET + 255) / 256;
    k_zero<<<(N + 255) / 256, 256, 0, stream>>>(CNT, N);
    k_hist<<<etGrid, 256, 0, stream>>>(ei, E, N, CNT);
    k_scan<<<1, 1024, 0, stream>>>(CNT, RS, CUR, N);
    k_fill<<<etGrid, 256, 0, stream>>>(ei, E, N, CUR, EIDX);

    const size_t a1_off = (size_t)N;
    const size_t a2_off = (size_t)N + (size_t)ET * 4;
    const int eh4Grid = (ET * 4 + 255) / 256;
    const int nh4Grid = (N * 4 + 255) / 256;

    k_encoder<<<N, 128, 0, stream>>>(d_in[0], encW, encb, FLAG, Hb);

    // ---- GAT layer 1: h=Hb -> xl,xr -> h1 back into Hb (relu) ----
    k_gemm2<<<N, 128, 0, stream>>>(Hb, w1l, b1l, w1r, b1r, XL, XR);
    k_scoreE<<<eh4Grid, 256, 0, stream>>>(XL, XR, ei, E, N, att1, EX);
    k_den<<<nh4Grid, 256, 0, stream>>>(EX, RS, EIDX, N, ET, INV);
    k_alpha<<<eh4Grid, 256, 0, stream>>>(EX, INV, ei, E, N, d_out, a1_off, FLAG);
    k_aggC<<<N, 64, 0, stream>>>(XL, EX, INV, RS, EIDX, ei, E, N, ET, bo1, 1, Hb);

    // ---- GAT layer 2: h=Hb -> xl,xr -> h2 back into Hb (no relu) ----
    k_gemm2<<<N, 128, 0, stream>>>(Hb, w2l, b2l, w2r, b2r, XL, XR);
    k_scoreE<<<eh4Grid, 256, 0, stream>>>(XL, XR, ei, E, N, att2, EX);
    k_den<<<nh4Grid, 256, 0, stream>>>(EX, RS, EIDX, N, ET, INV);
    k_alpha<<<eh4Grid, 256, 0, stream>>>(EX, INV, ei, E, N, d_out, a2_off, FLAG);
    k_aggC<<<N, 64, 0, stream>>>(XL, EX, INV, RS, EIDX, ei, E, N, ET, bo2, 0, Hb);

    k_mlp<<<N, 128, 0, stream>>>(Hb, mW1, mb1, mW2, mb2, d_out, FLAG);
}

// Round 6
// 883.714 us; speedup vs baseline: 13.9873x; 1.4686x over previous
//
#include <hip/hip_runtime.h>
#include <hip/hip_bf16.h>

#define NEG_SLOPE 0.2f
#define AS 136   // padded LDS row stride (bf16 elems): breaks 128-stride bank conflicts

typedef __bf16 bf16x8 __attribute__((ext_vector_type(8)));
typedef float  f32x4  __attribute__((ext_vector_type(4)));

__device__ __forceinline__ float b2f(__hip_bfloat16 v) { return __bfloat162float(v); }
__device__ __forceinline__ __hip_bfloat16 f2b(float v) { return __float2bfloat16(v); }
__device__ __forceinline__ float lo16(unsigned u) { return __uint_as_float(u << 16); }
__device__ __forceinline__ float hi16(unsigned u) { return __uint_as_float(u & 0xFFFF0000u); }

// ---- dtype detection (UNCHANGED — works; do not touch) --------------------
__global__ void k_detect(const unsigned short* __restrict__ w, int n, int* __restrict__ flag) {
    __shared__ int sh[256];
    int cnt = 0;
    for (int i = threadIdx.x * 2; i < n; i += 512) {   // even indices only
        int e = (w[i] >> 7) & 0xFF;
        if (e == 0 || e >= 0xC0) cnt++;
    }
    sh[threadIdx.x] = cnt;
    __syncthreads();
    for (int off = 128; off >= 1; off >>= 1) {
        if (threadIdx.x < off) sh[threadIdx.x] += sh[threadIdx.x + off];
        __syncthreads();
    }
    if (threadIdx.x == 0) *flag = (sh[0] > 128) ? 1 : 0;
}

__global__ void k_cvt(const void* __restrict__ src, float* __restrict__ dst, int n,
                      const int* __restrict__ flag) {
    int i = blockIdx.x * blockDim.x + threadIdx.x;
    if (i >= n) return;
    dst[i] = (*flag) ? ((const float*)src)[i]
                     : b2f(((const __hip_bfloat16*)src)[i]);
}

// convert+transpose a 128x128 weight into bf16 Wt[c][k]
__global__ void k_cvtWt(const void* __restrict__ src, __hip_bfloat16* __restrict__ dst,
                        const int* __restrict__ flag) {
    int k = blockIdx.x, c = threadIdx.x;
    float v = (*flag) ? ((const float*)src)[k * 128 + c]
                      : b2f(((const __hip_bfloat16*)src)[k * 128 + c]);
    dst[c * 128 + k] = f2b(v);
}

__device__ __forceinline__ void store_out(void* out, size_t idx, float v, int isF32) {
    if (isF32) ((float*)out)[idx] = v;
    else       ((__hip_bfloat16*)out)[idx] = f2b(v);
}

// ---------------- CSR build (by dst), once per call -----------------------
__global__ void k_zero(int* __restrict__ p, int n) {
    int i = blockIdx.x * blockDim.x + threadIdx.x;
    if (i < n) p[i] = 0;
}

__global__ void k_hist(const int* __restrict__ ei, int E, int N, int* __restrict__ cnt) {
    int e = blockIdx.x * blockDim.x + threadIdx.x;
    if (e >= E + N) return;
    int d = (e < E) ? ei[E + e] : (e - E);
    if ((unsigned)d >= (unsigned)N) return;
    atomicAdd(&cnt[d], 1);
}

__global__ __launch_bounds__(1024) void k_scan(const int* __restrict__ cnt,
                                               int* __restrict__ rs, int* __restrict__ cur, int N) {
    __shared__ int sums[1024];
    const int T = 1024, t = threadIdx.x;
    int chunk = (N + T - 1) / T;
    int beg = t * chunk, end = min(beg + chunk, N);
    int s = 0;
    for (int i = beg; i < end; ++i) s += cnt[i];
    sums[t] = s;
    __syncthreads();
    for (int off = 1; off < T; off <<= 1) {
        int v = (t >= off) ? sums[t - off] : 0;
        __syncthreads();
        sums[t] += v;
        __syncthreads();
    }
    int run = (t == 0) ? 0 : sums[t - 1];
    for (int i = beg; i < end; ++i) { rs[i] = run; cur[i] = run; run += cnt[i]; }
    if (t == T - 1) rs[N] = run;
}

__global__ void k_fill(const int* __restrict__ ei, int E, int N,
                       int* __restrict__ cur, int* __restrict__ eidx) {
    int e = blockIdx.x * blockDim.x + threadIdx.x;
    if (e >= E + N) return;
    int d = (e < E) ? ei[E + e] : (e - E);
    if ((unsigned)d >= (unsigned)N) return;
    int pos = atomicAdd(&cur[d], 1);
    eidx[pos] = e;
}

// ---------------- encoder: h = x @ enc_W + enc_b --------------------------
__global__ void k_encoder(const void* __restrict__ x, const float* __restrict__ W,
                          const float* __restrict__ b, const int* __restrict__ flag,
                          __hip_bfloat16* __restrict__ h) {
    int n = blockIdx.x, j = threadIdx.x;
    __shared__ float xs[16];
    if (j < 16)
        xs[j] = (*flag) ? ((const float*)x)[n * 16 + j]
                        : b2f(((const __hip_bfloat16*)x)[n * 16 + j]);
    __syncthreads();
    float acc = b[j];
#pragma unroll
    for (int k = 0; k < 16; ++k) acc += xs[k] * W[k * 128 + j];
    h[(size_t)n * 128 + j] = f2b(acc);
}

// --------- MFMA GEMM: out[r][c] = in[r][:]@W[:][c] + bias[c], 64 rows/blk --
// Wt is bf16 TRANSPOSED [c][k]. A-frag: A[m=lane&15][k=quad*8+j];
// B-frag: B[k=quad*8+j][n=lane&15]; C/D: col=lane&15, row=quad*4+reg.
__global__ __launch_bounds__(256) void k_gemm_mfma(
        const __hip_bfloat16* __restrict__ in, const __hip_bfloat16* __restrict__ Wt,
        const float* __restrict__ bias, int N, __hip_bfloat16* __restrict__ out) {
    __shared__ __hip_bfloat16 hA[64 * AS];
    __shared__ __hip_bfloat16 wB[128 * AS];
    int t = threadIdx.x, rbase = blockIdx.x * 64;
    for (int i = t; i < 2048; i += 256) {          // stage Wt (32 KB)
        int c = i >> 4, seg = i & 15;
        ((uint4*)(wB + c * AS))[seg] = ((const uint4*)(Wt + c * 128))[seg];
    }
    for (int i = t; i < 1024; i += 256) {          // stage 64 h rows (16 KB)
        int r = i >> 4, seg = i & 15;
        int gr = rbase + r;
        uint4 v = {0u, 0u, 0u, 0u};
        if (gr < N) v = ((const uint4*)(in + (size_t)gr * 128))[seg];
        ((uint4*)(hA + r * AS))[seg] = v;
    }
    __syncthreads();
    int wave = t >> 6, lane = t & 63, l16 = lane & 15, kq = lane >> 4;
    f32x4 acc[8];
#pragma unroll
    for (int i = 0; i < 8; ++i) acc[i] = (f32x4){0.f, 0.f, 0.f, 0.f};
#pragma unroll
    for (int ks = 0; ks < 4; ++ks) {
        int kofs = ks * 32 + kq * 8;
        bf16x8 a = *(const bf16x8*)(hA + (wave * 16 + l16) * AS + kofs);
#pragma unroll
        for (int cb = 0; cb < 8; ++cb) {
            bf16x8 b = *(const bf16x8*)(wB + (cb * 16 + l16) * AS + kofs);
            acc[cb] = __builtin_amdgcn_mfma_f32_16x16x32_bf16(a, b, acc[cb], 0, 0, 0);
        }
    }
#pragma unroll
    for (int cb = 0; cb < 8; ++cb) {
        int c = cb * 16 + l16;
        float bc = bias[c];
#pragma unroll
        for (int i = 0; i < 4; ++i) {
            int r = rbase + wave * 16 + kq * 4 + i;
            if (r < N) out[(size_t)r * 128 + c] = f2b(acc[cb][i] + bc);
        }
    }
}

// --------- MFMA MLP head: sigmoid(relu(h2@W1+b1)@W2 + b2), fused ----------
__global__ __launch_bounds__(256) void k_mlp_mfma(
        const __hip_bfloat16* __restrict__ h2, const __hip_bfloat16* __restrict__ W1t,
        const float* __restrict__ b1, const float* __restrict__ W2,
        const float* __restrict__ b2, int N,
        void* __restrict__ d_out, const int* __restrict__ flag) {
    __shared__ __hip_bfloat16 hA[64 * AS];
    __shared__ __hip_bfloat16 wB[128 * AS];
    int t = threadIdx.x, rbase = blockIdx.x * 64;
    for (int i = t; i < 2048; i += 256) {
        int c = i >> 4, seg = i & 15;
        ((uint4*)(wB + c * AS))[seg] = ((const uint4*)(W1t + c * 128))[seg];
    }
    for (int i = t; i < 1024; i += 256) {
        int r = i >> 4, seg = i & 15;
        int gr = rbase + r;
        uint4 v = {0u, 0u, 0u, 0u};
        if (gr < N) v = ((const uint4*)(h2 + (size_t)gr * 128))[seg];
        ((uint4*)(hA + r * AS))[seg] = v;
    }
    __syncthreads();
    int wave = t >> 6, lane = t & 63, l16 = lane & 15, kq = lane >> 4;
    f32x4 acc[8];
#pragma unroll
    for (int i = 0; i < 8; ++i) acc[i] = (f32x4){0.f, 0.f, 0.f, 0.f};
#pragma unroll
    for (int ks = 0; ks < 4; ++ks) {
        int kofs = ks * 32 + kq * 8;
        bf16x8 a = *(const bf16x8*)(hA + (wave * 16 + l16) * AS + kofs);
#pragma unroll
        for (int cb = 0; cb < 8; ++cb) {
            bf16x8 b = *(const bf16x8*)(wB + (cb * 16 + l16) * AS + kofs);
            acc[cb] = __builtin_amdgcn_mfma_f32_16x16x32_bf16(a, b, acc[cb], 0, 0, 0);
        }
    }
    float p[4] = {0.f, 0.f, 0.f, 0.f};
#pragma unroll
    for (int cb = 0; cb < 8; ++cb) {
        int c = cb * 16 + l16;
        float bb = b1[c], w = W2[c];
#pragma unroll
        for (int i = 0; i < 4; ++i) p[i] += fmaxf(acc[cb][i] + bb, 0.f) * w;
    }
#pragma unroll
    for (int i = 0; i < 4; ++i) {
        p[i] += __shfl_xor(p[i], 8, 16);
        p[i] += __shfl_xor(p[i], 4, 16);
        p[i] += __shfl_xor(p[i], 2, 16);
        p[i] += __shfl_xor(p[i], 1, 16);
    }
    if (l16 == 0) {
        int isF32 = *flag;
        float bb = b2[0];
#pragma unroll
        for (int i = 0; i < 4; ++i) {
            int r = rbase + wave * 16 + kq * 4 + i;
            if (r < N) store_out(d_out, (size_t)r, 1.f / (1.f + expf(-(p[i] + bb))), isF32);
        }
    }
}

// ---------------- per (edge,head): EX = exp(clamped score) ----------------
__global__ void k_scoreE(const __hip_bfloat16* __restrict__ xl,
                         const __hip_bfloat16* __restrict__ xr,
                         const int* __restrict__ ei, int E, int N,
                         const float* __restrict__ att,
                         float* __restrict__ EX) {
    int idx = blockIdx.x * blockDim.x + threadIdx.x;
    int ET4 = (E + N) * 4;
    if (idx >= ET4) return;
    int e = idx >> 2, h = idx & 3;
    int s, d;
    if (e < E) { s = ei[e]; d = ei[E + e]; } else { s = d = e - E; }
    if ((unsigned)s >= (unsigned)N || (unsigned)d >= (unsigned)N) { EX[idx] = 0.f; return; }
    const uint4* pl = (const uint4*)(xl + (size_t)s * 128 + h * 32);
    const uint4* pr = (const uint4*)(xr + (size_t)d * 128 + h * 32);
    const float* pa = att + h * 32;
    float sc = 0.f;
#pragma unroll
    for (int i = 0; i < 4; ++i) {
        uint4 a = pl[i], b = pr[i];
        const float* aa = pa + i * 8;
        float v0, v1;
        v0 = lo16(a.x) + lo16(b.x); v0 = (v0 > 0.f) ? v0 : NEG_SLOPE * v0;
        v1 = hi16(a.x) + hi16(b.x); v1 = (v1 > 0.f) ? v1 : NEG_SLOPE * v1;
        sc += v0 * aa[0] + v1 * aa[1];
        v0 = lo16(a.y) + lo16(b.y); v0 = (v0 > 0.f) ? v0 : NEG_SLOPE * v0;
        v1 = hi16(a.y) + hi16(b.y); v1 = (v1 > 0.f) ? v1 : NEG_SLOPE * v1;
        sc += v0 * aa[2] + v1 * aa[3];
        v0 = lo16(a.z) + lo16(b.z); v0 = (v0 > 0.f) ? v0 : NEG_SLOPE * v0;
        v1 = hi16(a.z) + hi16(b.z); v1 = (v1 > 0.f) ? v1 : NEG_SLOPE * v1;
        sc += v0 * aa[4] + v1 * aa[5];
        v0 = lo16(a.w) + lo16(b.w); v0 = (v0 > 0.f) ? v0 : NEG_SLOPE * v0;
        v1 = hi16(a.w) + hi16(b.w); v1 = (v1 > 0.f) ? v1 : NEG_SLOPE * v1;
        sc += v0 * aa[6] + v1 * aa[7];
    }
    sc = fminf(fmaxf(sc, -30.f), 30.f);
    EX[idx] = expf(sc);
}

// ---------------- per (node,head): inv_den (CSR, no atomics) --------------
__global__ void k_den(const float* __restrict__ EX, const int* __restrict__ rs,
                      const int* __restrict__ eidx, int N, int ET,
                      float* __restrict__ inv) {
    int idx = blockIdx.x * blockDim.x + threadIdx.x;
    if (idx >= N * 4) return;
    int n = idx >> 2, h = idx & 3;
    int beg = rs[n], end = rs[n + 1];
    float s = 0.f;
    for (int r = beg; r < end; ++r) {
        int eid = eidx[r];
        if ((unsigned)eid >= (unsigned)ET) continue;
        s += EX[(size_t)eid * 4 + h];
    }
    inv[idx] = 1.f / fmaxf(s, 1e-30f);
}

// ---------------- per (edge,head): alpha -> output tensor -----------------
__global__ void k_alpha(const float* __restrict__ EX, const float* __restrict__ inv,
                        const int* __restrict__ ei, int E, int N,
                        void* __restrict__ d_out, size_t aoff, const int* __restrict__ flag) {
    int idx = blockIdx.x * blockDim.x + threadIdx.x;
    int ET4 = (E + N) * 4;
    if (idx >= ET4) return;
    int e = idx >> 2, h = idx & 3;
    int d = (e < E) ? ei[E + e] : (e - E);
    float a = 0.f;
    if ((unsigned)d < (unsigned)N) a = EX[idx] * inv[(size_t)d * 4 + h];
    store_out(d_out, aoff + idx, a, *flag);
}

// ------- one wave per dst node: hout = (relu?)(sum alpha*xl[src] + bo) ----
__global__ __launch_bounds__(64) void k_aggC(
        const __hip_bfloat16* __restrict__ xl,
        const float* __restrict__ EX, const float* __restrict__ inv,
        const int* __restrict__ rs, const int* __restrict__ eidx,
        const int* __restrict__ ei, int E, int N, int ET,
        const float* __restrict__ bo, int relu,
        __hip_bfloat16* __restrict__ hout) {
    int n = blockIdx.x, lane = threadIdx.x;
    int h = lane >> 4;
    float invn = inv[(size_t)n * 4 + h];
    int beg = rs[n], end = rs[n + 1];
    float a0 = 0.f, a1 = 0.f;
    for (int r = beg; r < end; ++r) {
        int eid = eidx[r];
        if ((unsigned)eid >= (unsigned)ET) continue;
        int s = (eid < E) ? ei[eid] : (eid - E);
        if ((unsigned)s >= (unsigned)N) continue;
        float alpha = EX[(size_t)eid * 4 + h] * invn;
        unsigned u = ((const unsigned*)(xl + (size_t)s * 128))[lane];
        a0 += alpha * lo16(u);
        a1 += alpha * hi16(u);
    }
    int c0 = lane * 2;
    float v0 = a0 + bo[c0], v1 = a1 + bo[c0 + 1];
    if (relu) { v0 = fmaxf(v0, 0.f); v1 = fmaxf(v1, 0.f); }
    __hip_bfloat16 h0 = f2b(v0), h1 = f2b(v1);
    ushort2 st;
    st.x = *(unsigned short*)&h0;
    st.y = *(unsigned short*)&h1;
    ((ushort2*)(hout + (size_t)n * 128))[lane] = st;
}

extern "C" void kernel_launch(void* const* d_in, const int* in_sizes, int n_in,
                              void* d_out, int out_size, void* d_ws, size_t ws_size,
                              hipStream_t stream) {
    const int* ei = (const int*)d_in[1];
    const int N  = in_sizes[0] / 16;
    const int E  = in_sizes[1] / 2;
    const int ET = E + N;

    // ---------------- workspace carve ------------------------------------
    float* P = (float*)d_ws;
    float* encW = P; P += 2048;  float* encb = P; P += 128;
    float* b1l  = P; P += 128;   float* b1r  = P; P += 128;
    float* att1 = P; P += 128;   float* bo1  = P; P += 128;
    float* b2l  = P; P += 128;   float* b2r  = P; P += 128;
    float* att2 = P; P += 128;   float* bo2  = P; P += 128;
    float* mb1  = P; P += 128;   float* mW2  = P; P += 128;
    float* mb2  = P; P += 4;
    int*  FLAG  = (int*)P; P += 4;
    int*  CNT   = (int*)P; P += N;
    int*  RS    = (int*)P; P += N + 1;
    int*  CUR   = (int*)P; P += N;
    int*  EIDX  = (int*)P; P += ET;
    float* EX   = P; P += (size_t)ET * 4;
    float* INV  = P; P += (size_t)N * 4;
    P = (float*)(((uintptr_t)P + 15) & ~(uintptr_t)15);   // 16B align
    __hip_bfloat16* W1Lt = (__hip_bfloat16*)P;            // 5 x 128*128 bf16
    __hip_bfloat16* W1Rt = W1Lt + 16384;
    __hip_bfloat16* W2Lt = W1Rt + 16384;
    __hip_bfloat16* W2Rt = W2Lt + 16384;
    __hip_bfloat16* MW1t = W2Rt + 16384;
    __hip_bfloat16* Hb   = MW1t + 16384;                  // N*128 bf16
    __hip_bfloat16* XL   = Hb + (size_t)N * 128;
    __hip_bfloat16* XR   = XL + (size_t)N * 128;

    // ---------------- dtype detect + convert params -----------------------
    k_detect<<<1, 256, 0, stream>>>((const unsigned short*)d_in[4], 2048, FLAG);

    struct Cvt { int idx; float* dst; int n; };
    const Cvt cv[] = {
        {4, encW, 2048}, {5, encb, 128},
        {7, b1l, 128}, {9, b1r, 128}, {10, att1, 128}, {11, bo1, 128},
        {13, b2l, 128}, {15, b2r, 128}, {16, att2, 128}, {17, bo2, 128},
        {19, mb1, 128}, {20, mW2, 128}, {21, mb2, 1},
    };
    for (const Cvt& c : cv)
        k_cvt<<<(c.n + 255) / 256, 256, 0, stream>>>(d_in[c.idx], c.dst, c.n, FLAG);

    k_cvtWt<<<128, 128, 0, stream>>>(d_in[6],  W1Lt, FLAG);
    k_cvtWt<<<128, 128, 0, stream>>>(d_in[8],  W1Rt, FLAG);
    k_cvtWt<<<128, 128, 0, stream>>>(d_in[12], W2Lt, FLAG);
    k_cvtWt<<<128, 128, 0, stream>>>(d_in[14], W2Rt, FLAG);
    k_cvtWt<<<128, 128, 0, stream>>>(d_in[18], MW1t, FLAG);

    // ---------------- CSR by dst ------------------------------------------
    const int etGrid = (ET + 255) / 256;
    k_zero<<<(N + 255) / 256, 256, 0, stream>>>(CNT, N);
    k_hist<<<etGrid, 256, 0, stream>>>(ei, E, N, CNT);
    k_scan<<<1, 1024, 0, stream>>>(CNT, RS, CUR, N);
    k_fill<<<etGrid, 256, 0, stream>>>(ei, E, N, CUR, EIDX);

    const size_t a1_off = (size_t)N;
    const size_t a2_off = (size_t)N + (size_t)ET * 4;
    const int eh4Grid = (ET * 4 + 255) / 256;
    const int nh4Grid = (N * 4 + 255) / 256;
    const int gGrid   = (N + 63) / 64;

    k_encoder<<<N, 128, 0, stream>>>(d_in[0], encW, encb, FLAG, Hb);

    // ---- GAT layer 1 ----
    k_gemm_mfma<<<gGrid, 256, 0, stream>>>(Hb, W1Lt, b1l, N, XL);
    k_gemm_mfma<<<gGrid, 256, 0, stream>>>(Hb, W1Rt, b1r, N, XR);
    k_scoreE<<<eh4Grid, 256, 0, stream>>>(XL, XR, ei, E, N, att1, EX);
    k_den<<<nh4Grid, 256, 0, stream>>>(EX, RS, EIDX, N, ET, INV);
    k_alpha<<<eh4Grid, 256, 0, stream>>>(EX, INV, ei, E, N, d_out, a1_off, FLAG);
    k_aggC<<<N, 64, 0, stream>>>(XL, EX, INV, RS, EIDX, ei, E, N, ET, bo1, 1, Hb);

    // ---- GAT layer 2 ----
    k_gemm_mfma<<<gGrid, 256, 0, stream>>>(Hb, W2Lt, b2l, N, XL);
    k_gemm_mfma<<<gGrid, 256, 0, stream>>>(Hb, W2Rt, b2r, N, XR);
    k_scoreE<<<eh4Grid, 256, 0, stream>>>(XL, XR, ei, E, N, att2, EX);
    k_den<<<nh4Grid, 256, 0, stream>>>(EX, RS, EIDX, N, ET, INV);
    k_alpha<<<eh4Grid, 256, 0, stream>>>(EX, INV, ei, E, N, d_out, a2_off, FLAG);
    k_aggC<<<N, 64, 0, stream>>>(XL, EX, INV, RS, EIDX, ei, E, N, ET, bo2, 0, Hb);

    k_mlp_mfma<<<gGrid, 256, 0, stream>>>(Hb, MW1t, mb1, mW2, mb2, N, d_out, FLAG);
}

// Round 7
// 773.743 us; speedup vs baseline: 15.9753x; 1.1421x over previous
//
#include <hip/hip_runtime.h>
#include <hip/hip_bf16.h>

#define NEG_SLOPE 0.2f
#define AS 136   // padded LDS row stride (bf16 elems): breaks 128-stride bank conflicts

typedef __bf16 bf16x8 __attribute__((ext_vector_type(8)));
typedef float  f32x4  __attribute__((ext_vector_type(4)));

__device__ __forceinline__ float b2f(__hip_bfloat16 v) { return __bfloat162float(v); }
__device__ __forceinline__ __hip_bfloat16 f2b(float v) { return __float2bfloat16(v); }
__device__ __forceinline__ float lo16(unsigned u) { return __uint_as_float(u << 16); }
__device__ __forceinline__ float hi16(unsigned u) { return __uint_as_float(u & 0xFFFF0000u); }

// ---- dtype detection (UNCHANGED — works; do not touch) --------------------
__global__ void k_detect(const unsigned short* __restrict__ w, int n, int* __restrict__ flag) {
    __shared__ int sh[256];
    int cnt = 0;
    for (int i = threadIdx.x * 2; i < n; i += 512) {   // even indices only
        int e = (w[i] >> 7) & 0xFF;
        if (e == 0 || e >= 0xC0) cnt++;
    }
    sh[threadIdx.x] = cnt;
    __syncthreads();
    for (int off = 128; off >= 1; off >>= 1) {
        if (threadIdx.x < off) sh[threadIdx.x] += sh[threadIdx.x + off];
        __syncthreads();
    }
    if (threadIdx.x == 0) *flag = (sh[0] > 128) ? 1 : 0;
}

// ---- fused conversion of all small fp tensors (one launch) ----------------
#define NCVT 13
struct CvtTab {
    const void* src[NCVT];
    float*      dst[NCVT];
    int         n[NCVT];
    int         total;
};
__global__ void k_cvt_all(CvtTab tab, const int* __restrict__ flag) {
    int i = blockIdx.x * blockDim.x + threadIdx.x;
    if (i >= tab.total) return;
    int seg = 0, rem = i;
    while (rem >= tab.n[seg]) { rem -= tab.n[seg]; ++seg; }
    float v = (*flag) ? ((const float*)tab.src[seg])[rem]
                      : b2f(((const __hip_bfloat16*)tab.src[seg])[rem]);
    tab.dst[seg][rem] = v;
}

// ---- fused convert+transpose of the 5 128x128 weights (one launch) --------
struct WtTab { const void* src[5]; __hip_bfloat16* dst[5]; };
__global__ void k_cvtWt_all(WtTab tab, const int* __restrict__ flag) {
    int m = blockIdx.x >> 7;           // 128 blocks per matrix
    int k = blockIdx.x & 127, c = threadIdx.x;
    float v = (*flag) ? ((const float*)tab.src[m])[k * 128 + c]
                      : b2f(((const __hip_bfloat16*)tab.src[m])[k * 128 + c]);
    tab.dst[m][c * 128 + k] = f2b(v);
}

__device__ __forceinline__ void store_out(void* out, size_t idx, float v, int isF32) {
    if (isF32) ((float*)out)[idx] = v;
    else       ((__hip_bfloat16*)out)[idx] = f2b(v);
}

// ---------------- CSR build (by dst), once per call -----------------------
__global__ void k_zero(int* __restrict__ p, int n) {
    int i = blockIdx.x * blockDim.x + threadIdx.x;
    if (i < n) p[i] = 0;
}

__global__ void k_hist(const int* __restrict__ ei, int E, int N, int* __restrict__ cnt) {
    int e = blockIdx.x * blockDim.x + threadIdx.x;
    if (e >= E + N) return;
    int d = (e < E) ? ei[E + e] : (e - E);
    if ((unsigned)d >= (unsigned)N) return;
    atomicAdd(&cnt[d], 1);
}

// ---- 3-phase parallel exclusive scan (replaces single-block k_scan) ------
__global__ __launch_bounds__(256) void k_scanA(const int* __restrict__ cnt, int N,
                                               int* __restrict__ rs, int* __restrict__ bsum) {
    __shared__ int sh[256];
    int t = threadIdx.x, i = blockIdx.x * 256 + t;
    int v = (i < N) ? cnt[i] : 0;
    sh[t] = v;
    __syncthreads();
    for (int off = 1; off < 256; off <<= 1) {
        int u = (t >= off) ? sh[t - off] : 0;
        __syncthreads();
        sh[t] += u;
        __syncthreads();
    }
    if (i < N) rs[i] = sh[t] - v;                    // block-local exclusive
    if (t == 255) bsum[blockIdx.x] = sh[255];
}

__global__ __launch_bounds__(1024) void k_scanB(int* __restrict__ bsum, int B,
                                                int* __restrict__ rs, int N) {
    __shared__ int sh[1024];
    int t = threadIdx.x;
    int carry = 0;
    for (int base = 0; base < B; base += 1024) {
        int idx = base + t;
        int v = (idx < B) ? bsum[idx] : 0;
        sh[t] = v;
        __syncthreads();
        for (int off = 1; off < 1024; off <<= 1) {
            int u = (t >= off) ? sh[t - off] : 0;
            __syncthreads();
            sh[t] += u;
            __syncthreads();
        }
        if (idx < B) bsum[idx] = carry + sh[t] - v;  // global exclusive
        carry += sh[1023];
        __syncthreads();
    }
    if (t == 0) rs[N] = carry;                       // total
}

__global__ __launch_bounds__(256) void k_scanC(int* __restrict__ rs, int* __restrict__ cur,
                                               const int* __restrict__ bsum, int N) {
    int i = blockIdx.x * 256 + threadIdx.x;
    if (i >= N) return;
    int v = rs[i] + bsum[blockIdx.x];
    rs[i] = v;
    cur[i] = v;
}

__global__ void k_fill(const int* __restrict__ ei, int E, int N,
                       int* __restrict__ cur, int* __restrict__ eidx) {
    int e = blockIdx.x * blockDim.x + threadIdx.x;
    if (e >= E + N) return;
    int d = (e < E) ? ei[E + e] : (e - E);
    if ((unsigned)d >= (unsigned)N) return;
    int pos = atomicAdd(&cur[d], 1);
    eidx[pos] = e;
}

// ---------------- encoder: h = x @ enc_W + enc_b --------------------------
__global__ void k_encoder(const void* __restrict__ x, const float* __restrict__ W,
                          const float* __restrict__ b, const int* __restrict__ flag,
                          __hip_bfloat16* __restrict__ h) {
    int n = blockIdx.x, j = threadIdx.x;
    __shared__ float xs[16];
    if (j < 16)
        xs[j] = (*flag) ? ((const float*)x)[n * 16 + j]
                        : b2f(((const __hip_bfloat16*)x)[n * 16 + j]);
    __syncthreads();
    float acc = b[j];
#pragma unroll
    for (int k = 0; k < 16; ++k) acc += xs[k] * W[k * 128 + j];
    h[(size_t)n * 128 + j] = f2b(acc);
}

// --------- MFMA GEMM: out[r][c] = in[r][:]@W[:][c] + bias[c], 64 rows/blk --
__global__ __launch_bounds__(256) void k_gemm_mfma(
        const __hip_bfloat16* __restrict__ in, const __hip_bfloat16* __restrict__ Wt,
        const float* __restrict__ bias, int N, __hip_bfloat16* __restrict__ out) {
    __shared__ __hip_bfloat16 hA[64 * AS];
    __shared__ __hip_bfloat16 wB[128 * AS];
    int t = threadIdx.x, rbase = blockIdx.x * 64;
    for (int i = t; i < 2048; i += 256) {          // stage Wt (32 KB)
        int c = i >> 4, seg = i & 15;
        ((uint4*)(wB + c * AS))[seg] = ((const uint4*)(Wt + c * 128))[seg];
    }
    for (int i = t; i < 1024; i += 256) {          // stage 64 h rows (16 KB)
        int r = i >> 4, seg = i & 15;
        int gr = rbase + r;
        uint4 v = {0u, 0u, 0u, 0u};
        if (gr < N) v = ((const uint4*)(in + (size_t)gr * 128))[seg];
        ((uint4*)(hA + r * AS))[seg] = v;
    }
    __syncthreads();
    int wave = t >> 6, lane = t & 63, l16 = lane & 15, kq = lane >> 4;
    f32x4 acc[8];
#pragma unroll
    for (int i = 0; i < 8; ++i) acc[i] = (f32x4){0.f, 0.f, 0.f, 0.f};
#pragma unroll
    for (int ks = 0; ks < 4; ++ks) {
        int kofs = ks * 32 + kq * 8;
        bf16x8 a = *(const bf16x8*)(hA + (wave * 16 + l16) * AS + kofs);
#pragma unroll
        for (int cb = 0; cb < 8; ++cb) {
            bf16x8 b = *(const bf16x8*)(wB + (cb * 16 + l16) * AS + kofs);
            acc[cb] = __builtin_amdgcn_mfma_f32_16x16x32_bf16(a, b, acc[cb], 0, 0, 0);
        }
    }
#pragma unroll
    for (int cb = 0; cb < 8; ++cb) {
        int c = cb * 16 + l16;
        float bc = bias[c];
#pragma unroll
        for (int i = 0; i < 4; ++i) {
            int r = rbase + wave * 16 + kq * 4 + i;
            if (r < N) out[(size_t)r * 128 + c] = f2b(acc[cb][i] + bc);
        }
    }
}

// --------- MFMA MLP head: sigmoid(relu(h2@W1+b1)@W2 + b2), fused ----------
__global__ __launch_bounds__(256) void k_mlp_mfma(
        const __hip_bfloat16* __restrict__ h2, const __hip_bfloat16* __restrict__ W1t,
        const float* __restrict__ b1, const float* __restrict__ W2,
        const float* __restrict__ b2, int N,
        void* __restrict__ d_out, const int* __restrict__ flag) {
    __shared__ __hip_bfloat16 hA[64 * AS];
    __shared__ __hip_bfloat16 wB[128 * AS];
    int t = threadIdx.x, rbase = blockIdx.x * 64;
    for (int i = t; i < 2048; i += 256) {
        int c = i >> 4, seg = i & 15;
        ((uint4*)(wB + c * AS))[seg] = ((const uint4*)(W1t + c * 128))[seg];
    }
    for (int i = t; i < 1024; i += 256) {
        int r = i >> 4, seg = i & 15;
        int gr = rbase + r;
        uint4 v = {0u, 0u, 0u, 0u};
        if (gr < N) v = ((const uint4*)(h2 + (size_t)gr * 128))[seg];
        ((uint4*)(hA + r * AS))[seg] = v;
    }
    __syncthreads();
    int wave = t >> 6, lane = t & 63, l16 = lane & 15, kq = lane >> 4;
    f32x4 acc[8];
#pragma unroll
    for (int i = 0; i < 8; ++i) acc[i] = (f32x4){0.f, 0.f, 0.f, 0.f};
#pragma unroll
    for (int ks = 0; ks < 4; ++ks) {
        int kofs = ks * 32 + kq * 8;
        bf16x8 a = *(const bf16x8*)(hA + (wave * 16 + l16) * AS + kofs);
#pragma unroll
        for (int cb = 0; cb < 8; ++cb) {
            bf16x8 b = *(const bf16x8*)(wB + (cb * 16 + l16) * AS + kofs);
            acc[cb] = __builtin_amdgcn_mfma_f32_16x16x32_bf16(a, b, acc[cb], 0, 0, 0);
        }
    }
    float p[4] = {0.f, 0.f, 0.f, 0.f};
#pragma unroll
    for (int cb = 0; cb < 8; ++cb) {
        int c = cb * 16 + l16;
        float bb = b1[c], w = W2[c];
#pragma unroll
        for (int i = 0; i < 4; ++i) p[i] += fmaxf(acc[cb][i] + bb, 0.f) * w;
    }
#pragma unroll
    for (int i = 0; i < 4; ++i) {
        p[i] += __shfl_xor(p[i], 8, 16);
        p[i] += __shfl_xor(p[i], 4, 16);
        p[i] += __shfl_xor(p[i], 2, 16);
        p[i] += __shfl_xor(p[i], 1, 16);
    }
    if (l16 == 0) {
        int isF32 = *flag;
        float bb = b2[0];
#pragma unroll
        for (int i = 0; i < 4; ++i) {
            int r = rbase + wave * 16 + kq * 4 + i;
            if (r < N) store_out(d_out, (size_t)r, 1.f / (1.f + expf(-(p[i] + bb))), isF32);
        }
    }
}

// ---------------- per (edge,head): EX = exp(clamped score) ----------------
__global__ void k_scoreE(const __hip_bfloat16* __restrict__ xl,
                         const __hip_bfloat16* __restrict__ xr,
                         const int* __restrict__ ei, int E, int N,
                         const float* __restrict__ att,
                         float* __restrict__ EX) {
    int idx = blockIdx.x * blockDim.x + threadIdx.x;
    int ET4 = (E + N) * 4;
    if (idx >= ET4) return;
    int e = idx >> 2, h = idx & 3;
    int s, d;
    if (e < E) { s = ei[e]; d = ei[E + e]; } else { s = d = e - E; }
    if ((unsigned)s >= (unsigned)N || (unsigned)d >= (unsigned)N) { EX[idx] = 0.f; return; }
    const uint4* pl = (const uint4*)(xl + (size_t)s * 128 + h * 32);
    const uint4* pr = (const uint4*)(xr + (size_t)d * 128 + h * 32);
    const float* pa = att + h * 32;
    float sc = 0.f;
#pragma unroll
    for (int i = 0; i < 4; ++i) {
        uint4 a = pl[i], b = pr[i];
        const float* aa = pa + i * 8;
        float v0, v1;
        v0 = lo16(a.x) + lo16(b.x); v0 = (v0 > 0.f) ? v0 : NEG_SLOPE * v0;
        v1 = hi16(a.x) + hi16(b.x); v1 = (v1 > 0.f) ? v1 : NEG_SLOPE * v1;
        sc += v0 * aa[0] + v1 * aa[1];
        v0 = lo16(a.y) + lo16(b.y); v0 = (v0 > 0.f) ? v0 : NEG_SLOPE * v0;
        v1 = hi16(a.y) + hi16(b.y); v1 = (v1 > 0.f) ? v1 : NEG_SLOPE * v1;
        sc += v0 * aa[2] + v1 * aa[3];
        v0 = lo16(a.z) + lo16(b.z); v0 = (v0 > 0.f) ? v0 : NEG_SLOPE * v0;
        v1 = hi16(a.z) + hi16(b.z); v1 = (v1 > 0.f) ? v1 : NEG_SLOPE * v1;
        sc += v0 * aa[4] + v1 * aa[5];
        v0 = lo16(a.w) + lo16(b.w); v0 = (v0 > 0.f) ? v0 : NEG_SLOPE * v0;
        v1 = hi16(a.w) + hi16(b.w); v1 = (v1 > 0.f) ? v1 : NEG_SLOPE * v1;
        sc += v0 * aa[6] + v1 * aa[7];
    }
    sc = fminf(fmaxf(sc, -30.f), 30.f);
    EX[idx] = expf(sc);
}

// ---------------- per (node,head): inv_den (CSR, no atomics) --------------
__global__ void k_den(const float* __restrict__ EX, const int* __restrict__ rs,
                      const int* __restrict__ eidx, int N, int ET,
                      float* __restrict__ inv) {
    int idx = blockIdx.x * blockDim.x + threadIdx.x;
    if (idx >= N * 4) return;
    int n = idx >> 2, h = idx & 3;
    int beg = rs[n], end = rs[n + 1];
    float s = 0.f;
    for (int r = beg; r < end; ++r) {
        int eid = eidx[r];
        if ((unsigned)eid >= (unsigned)ET) continue;
        s += EX[(size_t)eid * 4 + h];
    }
    inv[idx] = 1.f / fmaxf(s, 1e-30f);
}

// ---------------- per (edge,head): alpha -> output tensor -----------------
__global__ void k_alpha(const float* __restrict__ EX, const float* __restrict__ inv,
                        const int* __restrict__ ei, int E, int N,
                        void* __restrict__ d_out, size_t aoff, const int* __restrict__ flag) {
    int idx = blockIdx.x * blockDim.x + threadIdx.x;
    int ET4 = (E + N) * 4;
    if (idx >= ET4) return;
    int e = idx >> 2, h = idx & 3;
    int d = (e < E) ? ei[E + e] : (e - E);
    float a = 0.f;
    if ((unsigned)d < (unsigned)N) a = EX[idx] * inv[(size_t)d * 4 + h];
    store_out(d_out, aoff + idx, a, *flag);
}

// ------- one wave per dst node: hout = (relu?)(sum alpha*xl[src] + bo) ----
__global__ __launch_bounds__(64) void k_aggC(
        const __hip_bfloat16* __restrict__ xl,
        const float* __restrict__ EX, const float* __restrict__ inv,
        const int* __restrict__ rs, const int* __restrict__ eidx,
        const int* __restrict__ ei, int E, int N, int ET,
        const float* __restrict__ bo, int relu,
        __hip_bfloat16* __restrict__ hout) {
    int n = blockIdx.x, lane = threadIdx.x;
    int h = lane >> 4;
    float invn = inv[(size_t)n * 4 + h];
    int beg = rs[n], end = rs[n + 1];
    float a0 = 0.f, a1 = 0.f;
    for (int r = beg; r < end; ++r) {
        int eid = eidx[r];
        if ((unsigned)eid >= (unsigned)ET) continue;
        int s = (eid < E) ? ei[eid] : (eid - E);
        if ((unsigned)s >= (unsigned)N) continue;
        float alpha = EX[(size_t)eid * 4 + h] * invn;
        unsigned u = ((const unsigned*)(xl + (size_t)s * 128))[lane];
        a0 += alpha * lo16(u);
        a1 += alpha * hi16(u);
    }
    int c0 = lane * 2;
    float v0 = a0 + bo[c0], v1 = a1 + bo[c0 + 1];
    if (relu) { v0 = fmaxf(v0, 0.f); v1 = fmaxf(v1, 0.f); }
    __hip_bfloat16 h0 = f2b(v0), h1 = f2b(v1);
    ushort2 st;
    st.x = *(unsigned short*)&h0;
    st.y = *(unsigned short*)&h1;
    ((ushort2*)(hout + (size_t)n * 128))[lane] = st;
}

extern "C" void kernel_launch(void* const* d_in, const int* in_sizes, int n_in,
                              void* d_out, int out_size, void* d_ws, size_t ws_size,
                              hipStream_t stream) {
    const int* ei = (const int*)d_in[1];
    const int N  = in_sizes[0] / 16;
    const int E  = in_sizes[1] / 2;
    const int ET = E + N;
    const int NB = (N + 255) / 256;          // scan blocks

    // ---------------- workspace carve ------------------------------------
    float* P = (float*)d_ws;
    float* encW = P; P += 2048;  float* encb = P; P += 128;
    float* b1l  = P; P += 128;   float* b1r  = P; P += 128;
    float* att1 = P; P += 128;   float* bo1  = P; P += 128;
    float* b2l  = P; P += 128;   float* b2r  = P; P += 128;
    float* att2 = P; P += 128;   float* bo2  = P; P += 128;
    float* mb1  = P; P += 128;   float* mW2  = P; P += 128;
    float* mb2  = P; P += 4;
    int*  FLAG  = (int*)P; P += 4;
    int*  CNT   = (int*)P; P += N;
    int*  RS    = (int*)P; P += N + 1;
    int*  CUR   = (int*)P; P += N;
    int*  BSUM  = (int*)P; P += NB;
    int*  EIDX  = (int*)P; P += ET;
    float* EX   = P; P += (size_t)ET * 4;
    float* INV  = P; P += (size_t)N * 4;
    P = (float*)(((uintptr_t)P + 15) & ~(uintptr_t)15);   // 16B align
    __hip_bfloat16* W1Lt = (__hip_bfloat16*)P;            // 5 x 128*128 bf16
    __hip_bfloat16* W1Rt = W1Lt + 16384;
    __hip_bfloat16* W2Lt = W1Rt + 16384;
    __hip_bfloat16* W2Rt = W2Lt + 16384;
    __hip_bfloat16* MW1t = W2Rt + 16384;
    __hip_bfloat16* Hb   = MW1t + 16384;                  // N*128 bf16
    __hip_bfloat16* XL   = Hb + (size_t)N * 128;
    __hip_bfloat16* XR   = XL + (size_t)N * 128;

    // ---------------- dtype detect + fused param conversion ---------------
    k_detect<<<1, 256, 0, stream>>>((const unsigned short*)d_in[4], 2048, FLAG);

    CvtTab tab;
    const int srcIdx[NCVT] = {4, 5, 7, 9, 10, 11, 13, 15, 16, 17, 19, 20, 21};
    float* dsts[NCVT] = {encW, encb, b1l, b1r, att1, bo1, b2l, b2r, att2, bo2, mb1, mW2, mb2};
    const int ns[NCVT] = {2048, 128, 128, 128, 128, 128, 128, 128, 128, 128, 128, 128, 1};
    int tot = 0;
    for (int i = 0; i < NCVT; ++i) {
        tab.src[i] = d_in[srcIdx[i]];
        tab.dst[i] = dsts[i];
        tab.n[i] = ns[i];
        tot += ns[i];
    }
    tab.total = tot;
    k_cvt_all<<<(tot + 255) / 256, 256, 0, stream>>>(tab, FLAG);

    WtTab wt;
    wt.src[0] = d_in[6];  wt.dst[0] = W1Lt;
    wt.src[1] = d_in[8];  wt.dst[1] = W1Rt;
    wt.src[2] = d_in[12]; wt.dst[2] = W2Lt;
    wt.src[3] = d_in[14]; wt.dst[3] = W2Rt;
    wt.src[4] = d_in[18]; wt.dst[4] = MW1t;
    k_cvtWt_all<<<640, 128, 0, stream>>>(wt, FLAG);

    // ---------------- CSR by dst (parallel scan) --------------------------
    const int etGrid = (ET + 255) / 256;
    k_zero<<<NB, 256, 0, stream>>>(CNT, N);
    k_hist<<<etGrid, 256, 0, stream>>>(ei, E, N, CNT);
    k_scanA<<<NB, 256, 0, stream>>>(CNT, N, RS, BSUM);
    k_scanB<<<1, 1024, 0, stream>>>(BSUM, NB, RS, N);
    k_scanC<<<NB, 256, 0, stream>>>(RS, CUR, BSUM, N);
    k_fill<<<etGrid, 256, 0, stream>>>(ei, E, N, CUR, EIDX);

    const size_t a1_off = (size_t)N;
    const size_t a2_off = (size_t)N + (size_t)ET * 4;
    const int eh4Grid = (ET * 4 + 255) / 256;
    const int nh4Grid = (N * 4 + 255) / 256;
    const int gGrid   = (N + 63) / 64;

    k_encoder<<<N, 128, 0, stream>>>(d_in[0], encW, encb, FLAG, Hb);

    // ---- GAT layer 1 ----
    k_gemm_mfma<<<gGrid, 256, 0, stream>>>(Hb, W1Lt, b1l, N, XL);
    k_gemm_mfma<<<gGrid, 256, 0, stream>>>(Hb, W1Rt, b1r, N, XR);
    k_scoreE<<<eh4Grid, 256, 0, stream>>>(XL, XR, ei, E, N, att1, EX);
    k_den<<<nh4Grid, 256, 0, stream>>>(EX, RS, EIDX, N, ET, INV);
    k_alpha<<<eh4Grid, 256, 0, stream>>>(EX, INV, ei, E, N, d_out, a1_off, FLAG);
    k_aggC<<<N, 64, 0, stream>>>(XL, EX, INV, RS, EIDX, ei, E, N, ET, bo1, 1, Hb);

    // ---- GAT layer 2 ----
    k_gemm_mfma<<<gGrid, 256, 0, stream>>>(Hb, W2Lt, b2l, N, XL);
    k_gemm_mfma<<<gGrid, 256, 0, stream>>>(Hb, W2Rt, b2r, N, XR);
    k_scoreE<<<eh4Grid, 256, 0, stream>>>(XL, XR, ei, E, N, att2, EX);
    k_den<<<nh4Grid, 256, 0, stream>>>(EX, RS, EIDX, N, ET, INV);
    k_alpha<<<eh4Grid, 256, 0, stream>>>(EX, INV, ei, E, N, d_out, a2_off, FLAG);
    k_aggC<<<N, 64, 0, stream>>>(XL, EX, INV, RS, EIDX, ei, E, N, ET, bo2, 0, Hb);

    k_mlp_mfma<<<gGrid, 256, 0, stream>>>(Hb, MW1t, mb1, mW2, mb2, N, d_out, FLAG);
}

// Round 8
// 552.487 us; speedup vs baseline: 22.3730x; 1.4005x over previous
//
#include <hip/hip_runtime.h>
#include <hip/hip_bf16.h>

#define NEG_SLOPE 0.2f
#define AS 136   // padded LDS row stride (bf16 elems): breaks 128-stride bank conflicts

typedef __bf16 bf16x8 __attribute__((ext_vector_type(8)));
typedef float  f32x4  __attribute__((ext_vector_type(4)));

__device__ __forceinline__ float b2f(__hip_bfloat16 v) { return __bfloat162float(v); }
__device__ __forceinline__ __hip_bfloat16 f2b(float v) { return __float2bfloat16(v); }
__device__ __forceinline__ float lo16(unsigned u) { return __uint_as_float(u << 16); }
__device__ __forceinline__ float hi16(unsigned u) { return __uint_as_float(u & 0xFFFF0000u); }

// ---- dtype detection (UNCHANGED — works; do not touch) --------------------
__global__ void k_detect(const unsigned short* __restrict__ w, int n, int* __restrict__ flag) {
    __shared__ int sh[256];
    int cnt = 0;
    for (int i = threadIdx.x * 2; i < n; i += 512) {   // even indices only
        int e = (w[i] >> 7) & 0xFF;
        if (e == 0 || e >= 0xC0) cnt++;
    }
    sh[threadIdx.x] = cnt;
    __syncthreads();
    for (int off = 128; off >= 1; off >>= 1) {
        if (threadIdx.x < off) sh[threadIdx.x] += sh[threadIdx.x + off];
        __syncthreads();
    }
    if (threadIdx.x == 0) *flag = (sh[0] > 128) ? 1 : 0;
}

// ---- fused conversion of all small fp tensors (one launch) ----------------
#define NCVT 13
struct CvtTab {
    const void* src[NCVT];
    float*      dst[NCVT];
    int         n[NCVT];
    int         total;
};
__global__ void k_cvt_all(CvtTab tab, const int* __restrict__ flag) {
    int i = blockIdx.x * blockDim.x + threadIdx.x;
    if (i >= tab.total) return;
    int seg = 0, rem = i;
    while (rem >= tab.n[seg]) { rem -= tab.n[seg]; ++seg; }
    float v = (*flag) ? ((const float*)tab.src[seg])[rem]
                      : b2f(((const __hip_bfloat16*)tab.src[seg])[rem]);
    tab.dst[seg][rem] = v;
}

// ---- fused convert+transpose of the 5 128x128 weights (one launch) --------
struct WtTab { const void* src[5]; __hip_bfloat16* dst[5]; };
__global__ void k_cvtWt_all(WtTab tab, const int* __restrict__ flag) {
    int m = blockIdx.x >> 7;           // 128 blocks per matrix
    int k = blockIdx.x & 127, c = threadIdx.x;
    float v = (*flag) ? ((const float*)tab.src[m])[k * 128 + c]
                      : b2f(((const __hip_bfloat16*)tab.src[m])[k * 128 + c]);
    tab.dst[m][c * 128 + k] = f2b(v);
}

__device__ __forceinline__ void store_out(void* out, size_t idx, float v, int isF32) {
    if (isF32) ((float*)out)[idx] = v;
    else       ((__hip_bfloat16*)out)[idx] = f2b(v);
}

// ---------------- CSR build (by dst), once per call -----------------------
__global__ void k_zero(int* __restrict__ p, int n) {
    int i = blockIdx.x * blockDim.x + threadIdx.x;
    if (i < n) p[i] = 0;
}

__global__ void k_hist(const int* __restrict__ ei, int E, int N, int* __restrict__ cnt) {
    int e = blockIdx.x * blockDim.x + threadIdx.x;
    if (e >= E + N) return;
    int d = (e < E) ? ei[E + e] : (e - E);
    if ((unsigned)d >= (unsigned)N) return;
    atomicAdd(&cnt[d], 1);
}

// ---- 3-phase parallel exclusive scan -------------------------------------
__global__ __launch_bounds__(256) void k_scanA(const int* __restrict__ cnt, int N,
                                               int* __restrict__ rs, int* __restrict__ bsum) {
    __shared__ int sh[256];
    int t = threadIdx.x, i = blockIdx.x * 256 + t;
    int v = (i < N) ? cnt[i] : 0;
    sh[t] = v;
    __syncthreads();
    for (int off = 1; off < 256; off <<= 1) {
        int u = (t >= off) ? sh[t - off] : 0;
        __syncthreads();
        sh[t] += u;
        __syncthreads();
    }
    if (i < N) rs[i] = sh[t] - v;                    // block-local exclusive
    if (t == 255) bsum[blockIdx.x] = sh[255];
}

__global__ __launch_bounds__(1024) void k_scanB(int* __restrict__ bsum, int B,
                                                int* __restrict__ rs, int N) {
    __shared__ int sh[1024];
    int t = threadIdx.x;
    int carry = 0;
    for (int base = 0; base < B; base += 1024) {
        int idx = base + t;
        int v = (idx < B) ? bsum[idx] : 0;
        sh[t] = v;
        __syncthreads();
        for (int off = 1; off < 1024; off <<= 1) {
            int u = (t >= off) ? sh[t - off] : 0;
            __syncthreads();
            sh[t] += u;
            __syncthreads();
        }
        if (idx < B) bsum[idx] = carry + sh[t] - v;  // global exclusive
        carry += sh[1023];
        __syncthreads();
    }
    if (t == 0) rs[N] = carry;                       // total
}

__global__ __launch_bounds__(256) void k_scanC(int* __restrict__ rs, int* __restrict__ cur,
                                               const int* __restrict__ bsum, int N) {
    int i = blockIdx.x * 256 + threadIdx.x;
    if (i >= N) return;
    int v = rs[i] + bsum[blockIdx.x];
    rs[i] = v;
    cur[i] = v;
}

__global__ void k_fill(const int* __restrict__ ei, int E, int N,
                       int* __restrict__ cur, int* __restrict__ eidx,
                       int* __restrict__ srcc) {
    int e = blockIdx.x * blockDim.x + threadIdx.x;
    if (e >= E + N) return;
    int s, d;
    if (e < E) { s = ei[e]; d = ei[E + e]; } else { s = d = e - E; }
    if ((unsigned)d >= (unsigned)N) return;
    int pos = atomicAdd(&cur[d], 1);
    eidx[pos] = e;
    srcc[pos] = s;
}

// ---------------- encoder: h = x @ enc_W + enc_b --------------------------
__global__ void k_encoder(const void* __restrict__ x, const float* __restrict__ W,
                          const float* __restrict__ b, const int* __restrict__ flag,
                          __hip_bfloat16* __restrict__ h) {
    int n = blockIdx.x, j = threadIdx.x;
    __shared__ float xs[16];
    if (j < 16)
        xs[j] = (*flag) ? ((const float*)x)[n * 16 + j]
                        : b2f(((const __hip_bfloat16*)x)[n * 16 + j]);
    __syncthreads();
    float acc = b[j];
#pragma unroll
    for (int k = 0; k < 16; ++k) acc += xs[k] * W[k * 128 + j];
    h[(size_t)n * 128 + j] = f2b(acc);
}

// --------- MFMA GEMM: out[r][c] = in[r][:]@W[:][c] + bias[c], 64 rows/blk --
__global__ __launch_bounds__(256) void k_gemm_mfma(
        const __hip_bfloat16* __restrict__ in, const __hip_bfloat16* __restrict__ Wt,
        const float* __restrict__ bias, int N, __hip_bfloat16* __restrict__ out) {
    __shared__ __hip_bfloat16 hA[64 * AS];
    __shared__ __hip_bfloat16 wB[128 * AS];
    int t = threadIdx.x, rbase = blockIdx.x * 64;
    for (int i = t; i < 2048; i += 256) {          // stage Wt (32 KB)
        int c = i >> 4, seg = i & 15;
        ((uint4*)(wB + c * AS))[seg] = ((const uint4*)(Wt + c * 128))[seg];
    }
    for (int i = t; i < 1024; i += 256) {          // stage 64 h rows (16 KB)
        int r = i >> 4, seg = i & 15;
        int gr = rbase + r;
        uint4 v = {0u, 0u, 0u, 0u};
        if (gr < N) v = ((const uint4*)(in + (size_t)gr * 128))[seg];
        ((uint4*)(hA + r * AS))[seg] = v;
    }
    __syncthreads();
    int wave = t >> 6, lane = t & 63, l16 = lane & 15, kq = lane >> 4;
    f32x4 acc[8];
#pragma unroll
    for (int i = 0; i < 8; ++i) acc[i] = (f32x4){0.f, 0.f, 0.f, 0.f};
#pragma unroll
    for (int ks = 0; ks < 4; ++ks) {
        int kofs = ks * 32 + kq * 8;
        bf16x8 a = *(const bf16x8*)(hA + (wave * 16 + l16) * AS + kofs);
#pragma unroll
        for (int cb = 0; cb < 8; ++cb) {
            bf16x8 b = *(const bf16x8*)(wB + (cb * 16 + l16) * AS + kofs);
            acc[cb] = __builtin_amdgcn_mfma_f32_16x16x32_bf16(a, b, acc[cb], 0, 0, 0);
        }
    }
#pragma unroll
    for (int cb = 0; cb < 8; ++cb) {
        int c = cb * 16 + l16;
        float bc = bias[c];
#pragma unroll
        for (int i = 0; i < 4; ++i) {
            int r = rbase + wave * 16 + kq * 4 + i;
            if (r < N) out[(size_t)r * 128 + c] = f2b(acc[cb][i] + bc);
        }
    }
}

// --------- MFMA MLP head: sigmoid(relu(h2@W1+b1)@W2 + b2), fused ----------
__global__ __launch_bounds__(256) void k_mlp_mfma(
        const __hip_bfloat16* __restrict__ h2, const __hip_bfloat16* __restrict__ W1t,
        const float* __restrict__ b1, const float* __restrict__ W2,
        const float* __restrict__ b2, int N,
        void* __restrict__ d_out, const int* __restrict__ flag) {
    __shared__ __hip_bfloat16 hA[64 * AS];
    __shared__ __hip_bfloat16 wB[128 * AS];
    int t = threadIdx.x, rbase = blockIdx.x * 64;
    for (int i = t; i < 2048; i += 256) {
        int c = i >> 4, seg = i & 15;
        ((uint4*)(wB + c * AS))[seg] = ((const uint4*)(W1t + c * 128))[seg];
    }
    for (int i = t; i < 1024; i += 256) {
        int r = i >> 4, seg = i & 15;
        int gr = rbase + r;
        uint4 v = {0u, 0u, 0u, 0u};
        if (gr < N) v = ((const uint4*)(h2 + (size_t)gr * 128))[seg];
        ((uint4*)(hA + r * AS))[seg] = v;
    }
    __syncthreads();
    int wave = t >> 6, lane = t & 63, l16 = lane & 15, kq = lane >> 4;
    f32x4 acc[8];
#pragma unroll
    for (int i = 0; i < 8; ++i) acc[i] = (f32x4){0.f, 0.f, 0.f, 0.f};
#pragma unroll
    for (int ks = 0; ks < 4; ++ks) {
        int kofs = ks * 32 + kq * 8;
        bf16x8 a = *(const bf16x8*)(hA + (wave * 16 + l16) * AS + kofs);
#pragma unroll
        for (int cb = 0; cb < 8; ++cb) {
            bf16x8 b = *(const bf16x8*)(wB + (cb * 16 + l16) * AS + kofs);
            acc[cb] = __builtin_amdgcn_mfma_f32_16x16x32_bf16(a, b, acc[cb], 0, 0, 0);
        }
    }
    float p[4] = {0.f, 0.f, 0.f, 0.f};
#pragma unroll
    for (int cb = 0; cb < 8; ++cb) {
        int c = cb * 16 + l16;
        float bb = b1[c], w = W2[c];
#pragma unroll
        for (int i = 0; i < 4; ++i) p[i] += fmaxf(acc[cb][i] + bb, 0.f) * w;
    }
#pragma unroll
    for (int i = 0; i < 4; ++i) {
        p[i] += __shfl_xor(p[i], 8, 16);
        p[i] += __shfl_xor(p[i], 4, 16);
        p[i] += __shfl_xor(p[i], 2, 16);
        p[i] += __shfl_xor(p[i], 1, 16);
    }
    if (l16 == 0) {
        int isF32 = *flag;
        float bb = b2[0];
#pragma unroll
        for (int i = 0; i < 4; ++i) {
            int r = rbase + wave * 16 + kq * 4 + i;
            if (r < N) store_out(d_out, (size_t)r, 1.f / (1.f + expf(-(p[i] + bb))), isF32);
        }
    }
}

// ===== fused GAT edge pipeline: one wave per dst node =====================
// score+exp+den+aggregate in ONE pass over the dst's CSR edges using
//   sum(alpha*xl) = (1/sum ex) * sum(ex*xl)
// then a lane-parallel loop writes alpha to the output (original e-order).
// Lane layout: h = lane>>4 (head), each lane owns channels c0=lane*2, c0+1.
__global__ __launch_bounds__(256) void k_gat_fused(
        const __hip_bfloat16* __restrict__ xl,
        const __hip_bfloat16* __restrict__ xr,
        const int* __restrict__ rs, const int* __restrict__ srcc,
        const int* __restrict__ eidx, int N,
        const float* __restrict__ att, const float* __restrict__ bo, int relu,
        float* __restrict__ EX2,
        void* __restrict__ alpha_out, size_t aoff, const int* __restrict__ flag,
        __hip_bfloat16* __restrict__ hout) {
    int wv = threadIdx.x >> 6, lane = threadIdx.x & 63;
    int n = blockIdx.x * 4 + wv;
    if (n >= N) return;
    int h = lane >> 4, l16 = lane & 15, c0 = lane * 2;
    unsigned uxr = ((const unsigned*)(xr + (size_t)n * 128))[lane];
    float xr0 = lo16(uxr), xr1 = hi16(uxr);
    float a0 = att[c0], a1 = att[c0 + 1];
    int beg = rs[n], end = rs[n + 1];
    float den = 0.f, acc0 = 0.f, acc1 = 0.f;
    for (int r = beg; r < end; ++r) {
        int s = srcc[r];
        unsigned u = 0;
        if ((unsigned)s < (unsigned)N)
            u = ((const unsigned*)(xl + (size_t)s * 128))[lane];
        float x0 = lo16(u), x1 = hi16(u);
        float v0 = x0 + xr0; v0 = (v0 > 0.f) ? v0 : NEG_SLOPE * v0;
        float v1 = x1 + xr1; v1 = (v1 > 0.f) ? v1 : NEG_SLOPE * v1;
        float p = v0 * a0 + v1 * a1;
        p += __shfl_xor(p, 1, 16);     // butterfly: all 16 lanes get head sum
        p += __shfl_xor(p, 2, 16);
        p += __shfl_xor(p, 4, 16);
        p += __shfl_xor(p, 8, 16);
        p = fminf(fmaxf(p, -30.f), 30.f);
        float ex = expf(p);
        if (l16 == 0) EX2[(size_t)r * 4 + h] = ex;
        den  += ex;
        acc0 += ex * x0;
        acc1 += ex * x1;
    }
    float invn = 1.f / fmaxf(den, 1e-30f);
    // node output: relu?(acc*invn + bo)
    float v0 = acc0 * invn + bo[c0], v1 = acc1 * invn + bo[c0 + 1];
    if (relu) { v0 = fmaxf(v0, 0.f); v1 = fmaxf(v1, 0.f); }
    __hip_bfloat16 h0 = f2b(v0), h1 = f2b(v1);
    ushort2 st;
    st.x = *(unsigned short*)&h0;
    st.y = *(unsigned short*)&h1;
    ((ushort2*)(hout + (size_t)n * 128))[lane] = st;
    // alpha outputs: 16 edges in parallel, lane (h,l16) handles (r0+l16, h)
    int isF32 = *flag;
    for (int r0 = beg; r0 < end; r0 += 16) {
        int r = r0 + l16;
        if (r < end) {
            float alpha = EX2[(size_t)r * 4 + h] * invn;
            int e = eidx[r];
            store_out(alpha_out, aoff + (size_t)e * 4 + h, alpha, isF32);
        }
    }
}

extern "C" void kernel_launch(void* const* d_in, const int* in_sizes, int n_in,
                              void* d_out, int out_size, void* d_ws, size_t ws_size,
                              hipStream_t stream) {
    const int* ei = (const int*)d_in[1];
    const int N  = in_sizes[0] / 16;
    const int E  = in_sizes[1] / 2;
    const int ET = E + N;
    const int NB = (N + 255) / 256;          // scan blocks

    // ---------------- workspace carve ------------------------------------
    float* P = (float*)d_ws;
    float* encW = P; P += 2048;  float* encb = P; P += 128;
    float* b1l  = P; P += 128;   float* b1r  = P; P += 128;
    float* att1 = P; P += 128;   float* bo1  = P; P += 128;
    float* b2l  = P; P += 128;   float* b2r  = P; P += 128;
    float* att2 = P; P += 128;   float* bo2  = P; P += 128;
    float* mb1  = P; P += 128;   float* mW2  = P; P += 128;
    float* mb2  = P; P += 4;
    int*  FLAG  = (int*)P; P += 4;
    int*  CNT   = (int*)P; P += N;
    int*  RS    = (int*)P; P += N + 1;
    int*  CUR   = (int*)P; P += N;
    int*  BSUM  = (int*)P; P += NB;
    int*  EIDX  = (int*)P; P += ET;
    int*  SRC   = (int*)P; P += ET;
    float* EX2  = P; P += (size_t)ET * 4;
    P = (float*)(((uintptr_t)P + 15) & ~(uintptr_t)15);   // 16B align
    __hip_bfloat16* W1Lt = (__hip_bfloat16*)P;            // 5 x 128*128 bf16
    __hip_bfloat16* W1Rt = W1Lt + 16384;
    __hip_bfloat16* W2Lt = W1Rt + 16384;
    __hip_bfloat16* W2Rt = W2Lt + 16384;
    __hip_bfloat16* MW1t = W2Rt + 16384;
    __hip_bfloat16* Hb   = MW1t + 16384;                  // N*128 bf16
    __hip_bfloat16* XL   = Hb + (size_t)N * 128;
    __hip_bfloat16* XR   = XL + (size_t)N * 128;

    // ---------------- dtype detect + fused param conversion ---------------
    k_detect<<<1, 256, 0, stream>>>((const unsigned short*)d_in[4], 2048, FLAG);

    CvtTab tab;
    const int srcIdx[NCVT] = {4, 5, 7, 9, 10, 11, 13, 15, 16, 17, 19, 20, 21};
    float* dsts[NCVT] = {encW, encb, b1l, b1r, att1, bo1, b2l, b2r, att2, bo2, mb1, mW2, mb2};
    const int ns[NCVT] = {2048, 128, 128, 128, 128, 128, 128, 128, 128, 128, 128, 128, 1};
    int tot = 0;
    for (int i = 0; i < NCVT; ++i) {
        tab.src[i] = d_in[srcIdx[i]];
        tab.dst[i] = dsts[i];
        tab.n[i] = ns[i];
        tot += ns[i];
    }
    tab.total = tot;
    k_cvt_all<<<(tot + 255) / 256, 256, 0, stream>>>(tab, FLAG);

    WtTab wt;
    wt.src[0] = d_in[6];  wt.dst[0] = W1Lt;
    wt.src[1] = d_in[8];  wt.dst[1] = W1Rt;
    wt.src[2] = d_in[12]; wt.dst[2] = W2Lt;
    wt.src[3] = d_in[14]; wt.dst[3] = W2Rt;
    wt.src[4] = d_in[18]; wt.dst[4] = MW1t;
    k_cvtWt_all<<<640, 128, 0, stream>>>(wt, FLAG);

    // ---------------- CSR by dst (parallel scan) --------------------------
    const int etGrid = (ET + 255) / 256;
    k_zero<<<NB, 256, 0, stream>>>(CNT, N);
    k_hist<<<etGrid, 256, 0, stream>>>(ei, E, N, CNT);
    k_scanA<<<NB, 256, 0, stream>>>(CNT, N, RS, BSUM);
    k_scanB<<<1, 1024, 0, stream>>>(BSUM, NB, RS, N);
    k_scanC<<<NB, 256, 0, stream>>>(RS, CUR, BSUM, N);
    k_fill<<<etGrid, 256, 0, stream>>>(ei, E, N, CUR, EIDX, SRC);

    const size_t a1_off = (size_t)N;
    const size_t a2_off = (size_t)N + (size_t)ET * 4;
    const int gGrid = (N + 63) / 64;
    const int fGrid = (N + 3) / 4;

    k_encoder<<<N, 128, 0, stream>>>(d_in[0], encW, encb, FLAG, Hb);

    // ---- GAT layer 1 ----
    k_gemm_mfma<<<gGrid, 256, 0, stream>>>(Hb, W1Lt, b1l, N, XL);
    k_gemm_mfma<<<gGrid, 256, 0, stream>>>(Hb, W1Rt, b1r, N, XR);
    k_gat_fused<<<fGrid, 256, 0, stream>>>(XL, XR, RS, SRC, EIDX, N, att1, bo1, 1,
                                           EX2, d_out, a1_off, FLAG, Hb);

    // ---- GAT layer 2 ----
    k_gemm_mfma<<<gGrid, 256, 0, stream>>>(Hb, W2Lt, b2l, N, XL);
    k_gemm_mfma<<<gGrid, 256, 0, stream>>>(Hb, W2Rt, b2r, N, XR);
    k_gat_fused<<<fGrid, 256, 0, stream>>>(XL, XR, RS, SRC, EIDX, N, att2, bo2, 0,
                                           EX2, d_out, a2_off, FLAG, Hb);

    k_mlp_mfma<<<gGrid, 256, 0, stream>>>(Hb, MW1t, mb1, mW2, mb2, N, d_out, FLAG);
}

// Round 9
// 451.791 us; speedup vs baseline: 27.3596x; 1.2229x over previous
//
#include <hip/hip_runtime.h>
#include <hip/hip_bf16.h>

#define NEG_SLOPE 0.2f
#define AS 136   // padded LDS row stride (bf16 elems): breaks 128-stride bank conflicts

typedef __bf16 bf16x8 __attribute__((ext_vector_type(8)));
typedef float  f32x4  __attribute__((ext_vector_type(4)));

__device__ __forceinline__ float b2f(__hip_bfloat16 v) { return __bfloat162float(v); }
__device__ __forceinline__ __hip_bfloat16 f2b(float v) { return __float2bfloat16(v); }
__device__ __forceinline__ float lo16(unsigned u) { return __uint_as_float(u << 16); }
__device__ __forceinline__ float hi16(unsigned u) { return __uint_as_float(u & 0xFFFF0000u); }

// ---- dtype detection (UNCHANGED — works; do not touch) --------------------
__global__ void k_detect(const unsigned short* __restrict__ w, int n, int* __restrict__ flag) {
    __shared__ int sh[256];
    int cnt = 0;
    for (int i = threadIdx.x * 2; i < n; i += 512) {   // even indices only
        int e = (w[i] >> 7) & 0xFF;
        if (e == 0 || e >= 0xC0) cnt++;
    }
    sh[threadIdx.x] = cnt;
    __syncthreads();
    for (int off = 128; off >= 1; off >>= 1) {
        if (threadIdx.x < off) sh[threadIdx.x] += sh[threadIdx.x + off];
        __syncthreads();
    }
    if (threadIdx.x == 0) *flag = (sh[0] > 128) ? 1 : 0;
}

// ---- fused conversion of all small fp tensors (one launch) ----------------
#define NCVT 13
struct CvtTab {
    const void* src[NCVT];
    float*      dst[NCVT];
    int         n[NCVT];
    int         total;
};
__global__ void k_cvt_all(CvtTab tab, const int* __restrict__ flag) {
    int i = blockIdx.x * blockDim.x + threadIdx.x;
    if (i >= tab.total) return;
    int seg = 0, rem = i;
    while (rem >= tab.n[seg]) { rem -= tab.n[seg]; ++seg; }
    float v = (*flag) ? ((const float*)tab.src[seg])[rem]
                      : b2f(((const __hip_bfloat16*)tab.src[seg])[rem]);
    tab.dst[seg][rem] = v;
}

// ---- fused convert+transpose of the 5 128x128 weights (one launch) --------
struct WtTab { const void* src[5]; __hip_bfloat16* dst[5]; };
__global__ void k_cvtWt_all(WtTab tab, const int* __restrict__ flag) {
    int m = blockIdx.x >> 7;           // 128 blocks per matrix
    int k = blockIdx.x & 127, c = threadIdx.x;
    float v = (*flag) ? ((const float*)tab.src[m])[k * 128 + c]
                      : b2f(((const __hip_bfloat16*)tab.src[m])[k * 128 + c]);
    tab.dst[m][c * 128 + k] = f2b(v);
}

__device__ __forceinline__ void store_out(void* out, size_t idx, float v, int isF32) {
    if (isF32) ((float*)out)[idx] = v;
    else       ((__hip_bfloat16*)out)[idx] = f2b(v);
}

// ---------------- CSR build (by dst), once per call -----------------------
__global__ void k_zero(int* __restrict__ p, int n) {
    int i = blockIdx.x * blockDim.x + threadIdx.x;
    if (i < n) p[i] = 0;
}

__global__ void k_hist(const int* __restrict__ ei, int E, int N, int* __restrict__ cnt) {
    int e = blockIdx.x * blockDim.x + threadIdx.x;
    if (e >= E + N) return;
    int d = (e < E) ? ei[E + e] : (e - E);
    if ((unsigned)d >= (unsigned)N) return;
    atomicAdd(&cnt[d], 1);
}

// ---- 3-phase parallel exclusive scan -------------------------------------
__global__ __launch_bounds__(256) void k_scanA(const int* __restrict__ cnt, int N,
                                               int* __restrict__ rs, int* __restrict__ bsum) {
    __shared__ int sh[256];
    int t = threadIdx.x, i = blockIdx.x * 256 + t;
    int v = (i < N) ? cnt[i] : 0;
    sh[t] = v;
    __syncthreads();
    for (int off = 1; off < 256; off <<= 1) {
        int u = (t >= off) ? sh[t - off] : 0;
        __syncthreads();
        sh[t] += u;
        __syncthreads();
    }
    if (i < N) rs[i] = sh[t] - v;                    // block-local exclusive
    if (t == 255) bsum[blockIdx.x] = sh[255];
}

__global__ __launch_bounds__(1024) void k_scanB(int* __restrict__ bsum, int B,
                                                int* __restrict__ rs, int N) {
    __shared__ int sh[1024];
    int t = threadIdx.x;
    int carry = 0;
    for (int base = 0; base < B; base += 1024) {
        int idx = base + t;
        int v = (idx < B) ? bsum[idx] : 0;
        sh[t] = v;
        __syncthreads();
        for (int off = 1; off < 1024; off <<= 1) {
            int u = (t >= off) ? sh[t - off] : 0;
            __syncthreads();
            sh[t] += u;
            __syncthreads();
        }
        if (idx < B) bsum[idx] = carry + sh[t] - v;  // global exclusive
        carry += sh[1023];
        __syncthreads();
    }
    if (t == 0) rs[N] = carry;                       // total
}

__global__ __launch_bounds__(256) void k_scanC(int* __restrict__ rs, int* __restrict__ cur,
                                               const int* __restrict__ bsum, int N) {
    int i = blockIdx.x * 256 + threadIdx.x;
    if (i >= N) return;
    int v = rs[i] + bsum[blockIdx.x];
    rs[i] = v;
    cur[i] = v;
}

__global__ void k_fill(const int* __restrict__ ei, int E, int N,
                       int* __restrict__ cur, int* __restrict__ eidx,
                       int* __restrict__ srcc) {
    int e = blockIdx.x * blockDim.x + threadIdx.x;
    if (e >= E + N) return;
    int s, d;
    if (e < E) { s = ei[e]; d = ei[E + e]; } else { s = d = e - E; }
    if ((unsigned)d >= (unsigned)N) return;
    int pos = atomicAdd(&cur[d], 1);
    eidx[pos] = e;
    srcc[pos] = s;
}

// ---------------- encoder: h = x @ enc_W + enc_b --------------------------
__global__ void k_encoder(const void* __restrict__ x, const float* __restrict__ W,
                          const float* __restrict__ b, const int* __restrict__ flag,
                          __hip_bfloat16* __restrict__ h) {
    int n = blockIdx.x, j = threadIdx.x;
    __shared__ float xs[16];
    if (j < 16)
        xs[j] = (*flag) ? ((const float*)x)[n * 16 + j]
                        : b2f(((const __hip_bfloat16*)x)[n * 16 + j]);
    __syncthreads();
    float acc = b[j];
#pragma unroll
    for (int k = 0; k < 16; ++k) acc += xs[k] * W[k * 128 + j];
    h[(size_t)n * 128 + j] = f2b(acc);
}

// --- dual MFMA GEMM: stage hA once, loop over {Wl->xl, Wr->xr} -------------
__global__ __launch_bounds__(256) void k_gemm2_mfma(
        const __hip_bfloat16* __restrict__ in,
        const __hip_bfloat16* __restrict__ WLt, const float* __restrict__ bl,
        const __hip_bfloat16* __restrict__ WRt, const float* __restrict__ br,
        int N, __hip_bfloat16* __restrict__ xl, __hip_bfloat16* __restrict__ xr) {
    __shared__ __hip_bfloat16 hA[64 * AS];
    __shared__ __hip_bfloat16 wB[128 * AS];
    int t = threadIdx.x, rbase = blockIdx.x * 64;
    for (int i = t; i < 1024; i += 256) {          // stage 64 h rows (16 KB) ONCE
        int r = i >> 4, seg = i & 15;
        int gr = rbase + r;
        uint4 v = {0u, 0u, 0u, 0u};
        if (gr < N) v = ((const uint4*)(in + (size_t)gr * 128))[seg];
        ((uint4*)(hA + r * AS))[seg] = v;
    }
    int wave = t >> 6, lane = t & 63, l16 = lane & 15, kq = lane >> 4;
#pragma unroll
    for (int pass = 0; pass < 2; ++pass) {
        const __hip_bfloat16* Wt = pass ? WRt : WLt;
        const float* bias        = pass ? br  : bl;
        __hip_bfloat16* out      = pass ? xr  : xl;
        __syncthreads();                           // wB free (and hA staged on pass 0)
        for (int i = t; i < 2048; i += 256) {      // stage Wt (32 KB)
            int c = i >> 4, seg = i & 15;
            ((uint4*)(wB + c * AS))[seg] = ((const uint4*)(Wt + c * 128))[seg];
        }
        __syncthreads();
        f32x4 acc[8];
#pragma unroll
        for (int i = 0; i < 8; ++i) acc[i] = (f32x4){0.f, 0.f, 0.f, 0.f};
#pragma unroll
        for (int ks = 0; ks < 4; ++ks) {
            int kofs = ks * 32 + kq * 8;
            bf16x8 a = *(const bf16x8*)(hA + (wave * 16 + l16) * AS + kofs);
#pragma unroll
            for (int cb = 0; cb < 8; ++cb) {
                bf16x8 b = *(const bf16x8*)(wB + (cb * 16 + l16) * AS + kofs);
                acc[cb] = __builtin_amdgcn_mfma_f32_16x16x32_bf16(a, b, acc[cb], 0, 0, 0);
            }
        }
#pragma unroll
        for (int cb = 0; cb < 8; ++cb) {
            int c = cb * 16 + l16;
            float bc = bias[c];
#pragma unroll
            for (int i = 0; i < 4; ++i) {
                int r = rbase + wave * 16 + kq * 4 + i;
                if (r < N) out[(size_t)r * 128 + c] = f2b(acc[cb][i] + bc);
            }
        }
    }
}

// --------- MFMA MLP head: sigmoid(relu(h2@W1+b1)@W2 + b2), fused ----------
__global__ __launch_bounds__(256) void k_mlp_mfma(
        const __hip_bfloat16* __restrict__ h2, const __hip_bfloat16* __restrict__ W1t,
        const float* __restrict__ b1, const float* __restrict__ W2,
        const float* __restrict__ b2, int N,
        void* __restrict__ d_out, const int* __restrict__ flag) {
    __shared__ __hip_bfloat16 hA[64 * AS];
    __shared__ __hip_bfloat16 wB[128 * AS];
    int t = threadIdx.x, rbase = blockIdx.x * 64;
    for (int i = t; i < 2048; i += 256) {
        int c = i >> 4, seg = i & 15;
        ((uint4*)(wB + c * AS))[seg] = ((const uint4*)(W1t + c * 128))[seg];
    }
    for (int i = t; i < 1024; i += 256) {
        int r = i >> 4, seg = i & 15;
        int gr = rbase + r;
        uint4 v = {0u, 0u, 0u, 0u};
        if (gr < N) v = ((const uint4*)(h2 + (size_t)gr * 128))[seg];
        ((uint4*)(hA + r * AS))[seg] = v;
    }
    __syncthreads();
    int wave = t >> 6, lane = t & 63, l16 = lane & 15, kq = lane >> 4;
    f32x4 acc[8];
#pragma unroll
    for (int i = 0; i < 8; ++i) acc[i] = (f32x4){0.f, 0.f, 0.f, 0.f};
#pragma unroll
    for (int ks = 0; ks < 4; ++ks) {
        int kofs = ks * 32 + kq * 8;
        bf16x8 a = *(const bf16x8*)(hA + (wave * 16 + l16) * AS + kofs);
#pragma unroll
        for (int cb = 0; cb < 8; ++cb) {
            bf16x8 b = *(const bf16x8*)(wB + (cb * 16 + l16) * AS + kofs);
            acc[cb] = __builtin_amdgcn_mfma_f32_16x16x32_bf16(a, b, acc[cb], 0, 0, 0);
        }
    }
    float p[4] = {0.f, 0.f, 0.f, 0.f};
#pragma unroll
    for (int cb = 0; cb < 8; ++cb) {
        int c = cb * 16 + l16;
        float bb = b1[c], w = W2[c];
#pragma unroll
        for (int i = 0; i < 4; ++i) p[i] += fmaxf(acc[cb][i] + bb, 0.f) * w;
    }
#pragma unroll
    for (int i = 0; i < 4; ++i) {
        p[i] += __shfl_xor(p[i], 8, 16);
        p[i] += __shfl_xor(p[i], 4, 16);
        p[i] += __shfl_xor(p[i], 2, 16);
        p[i] += __shfl_xor(p[i], 1, 16);
    }
    if (l16 == 0) {
        int isF32 = *flag;
        float bb = b2[0];
#pragma unroll
        for (int i = 0; i < 4; ++i) {
            int r = rbase + wave * 16 + kq * 4 + i;
            if (r < N) store_out(d_out, (size_t)r, 1.f / (1.f + expf(-(p[i] + bb))), isF32);
        }
    }
}

// ===== fused GAT edge pipeline: one wave per dst, 4-way unrolled ==========
__device__ __forceinline__ float edge_p(unsigned u, float xr0, float xr1,
                                        float a0, float a1) {
    float v0 = lo16(u) + xr0; v0 = (v0 > 0.f) ? v0 : NEG_SLOPE * v0;
    float v1 = hi16(u) + xr1; v1 = (v1 > 0.f) ? v1 : NEG_SLOPE * v1;
    return v0 * a0 + v1 * a1;
}

__global__ __launch_bounds__(256) void k_gat_fused(
        const __hip_bfloat16* __restrict__ xl,
        const __hip_bfloat16* __restrict__ xr,
        const int* __restrict__ rs, const int* __restrict__ srcc,
        const int* __restrict__ eidx, int N,
        const float* __restrict__ att, const float* __restrict__ bo, int relu,
        float* __restrict__ EX2,
        void* __restrict__ alpha_out, size_t aoff, const int* __restrict__ flag,
        __hip_bfloat16* __restrict__ hout) {
    int wv = threadIdx.x >> 6, lane = threadIdx.x & 63;
    int n = blockIdx.x * 4 + wv;
    if (n >= N) return;
    int h = lane >> 4, l16 = lane & 15, c0 = lane * 2;
    unsigned uxr = ((const unsigned*)(xr + (size_t)n * 128))[lane];
    float xr0 = lo16(uxr), xr1 = hi16(uxr);
    float a0 = att[c0], a1 = att[c0 + 1];
    int beg = rs[n], end = rs[n + 1];
    float den = 0.f, acc0 = 0.f, acc1 = 0.f;
    int r = beg;
    for (; r + 4 <= end; r += 4) {                  // 4 independent edges in flight
        int s0 = srcc[r], s1 = srcc[r + 1], s2 = srcc[r + 2], s3 = srcc[r + 3];
        unsigned u0 = 0, u1 = 0, u2 = 0, u3 = 0;
        if ((unsigned)s0 < (unsigned)N) u0 = ((const unsigned*)(xl + (size_t)s0 * 128))[lane];
        if ((unsigned)s1 < (unsigned)N) u1 = ((const unsigned*)(xl + (size_t)s1 * 128))[lane];
        if ((unsigned)s2 < (unsigned)N) u2 = ((const unsigned*)(xl + (size_t)s2 * 128))[lane];
        if ((unsigned)s3 < (unsigned)N) u3 = ((const unsigned*)(xl + (size_t)s3 * 128))[lane];
        float p0 = edge_p(u0, xr0, xr1, a0, a1);
        float p1 = edge_p(u1, xr0, xr1, a0, a1);
        float p2 = edge_p(u2, xr0, xr1, a0, a1);
        float p3 = edge_p(u3, xr0, xr1, a0, a1);
        p0 += __shfl_xor(p0, 1, 16); p1 += __shfl_xor(p1, 1, 16);
        p2 += __shfl_xor(p2, 1, 16); p3 += __shfl_xor(p3, 1, 16);
        p0 += __shfl_xor(p0, 2, 16); p1 += __shfl_xor(p1, 2, 16);
        p2 += __shfl_xor(p2, 2, 16); p3 += __shfl_xor(p3, 2, 16);
        p0 += __shfl_xor(p0, 4, 16); p1 += __shfl_xor(p1, 4, 16);
        p2 += __shfl_xor(p2, 4, 16); p3 += __shfl_xor(p3, 4, 16);
        p0 += __shfl_xor(p0, 8, 16); p1 += __shfl_xor(p1, 8, 16);
        p2 += __shfl_xor(p2, 8, 16); p3 += __shfl_xor(p3, 8, 16);
        float ex0 = expf(fminf(fmaxf(p0, -30.f), 30.f));
        float ex1 = expf(fminf(fmaxf(p1, -30.f), 30.f));
        float ex2 = expf(fminf(fmaxf(p2, -30.f), 30.f));
        float ex3 = expf(fminf(fmaxf(p3, -30.f), 30.f));
        if (l16 == 0) {
            EX2[(size_t)r * 4 + h]       = ex0;
            EX2[(size_t)(r + 1) * 4 + h] = ex1;
            EX2[(size_t)(r + 2) * 4 + h] = ex2;
            EX2[(size_t)(r + 3) * 4 + h] = ex3;
        }
        den  += (ex0 + ex1) + (ex2 + ex3);
        acc0 += ex0 * lo16(u0) + ex1 * lo16(u1) + ex2 * lo16(u2) + ex3 * lo16(u3);
        acc1 += ex0 * hi16(u0) + ex1 * hi16(u1) + ex2 * hi16(u2) + ex3 * hi16(u3);
    }
    for (; r < end; ++r) {                          // tail (<=3)
        int s = srcc[r];
        unsigned u = 0;
        if ((unsigned)s < (unsigned)N) u = ((const unsigned*)(xl + (size_t)s * 128))[lane];
        float p = edge_p(u, xr0, xr1, a0, a1);
        p += __shfl_xor(p, 1, 16);
        p += __shfl_xor(p, 2, 16);
        p += __shfl_xor(p, 4, 16);
        p += __shfl_xor(p, 8, 16);
        float ex = expf(fminf(fmaxf(p, -30.f), 30.f));
        if (l16 == 0) EX2[(size_t)r * 4 + h] = ex;
        den  += ex;
        acc0 += ex * lo16(u);
        acc1 += ex * hi16(u);
    }
    float invn = 1.f / fmaxf(den, 1e-30f);
    float v0 = acc0 * invn + bo[c0], v1 = acc1 * invn + bo[c0 + 1];
    if (relu) { v0 = fmaxf(v0, 0.f); v1 = fmaxf(v1, 0.f); }
    __hip_bfloat16 h0 = f2b(v0), h1 = f2b(v1);
    ushort2 st;
    st.x = *(unsigned short*)&h0;
    st.y = *(unsigned short*)&h1;
    ((ushort2*)(hout + (size_t)n * 128))[lane] = st;
    // alpha outputs: 16 edges in parallel, lane (h,l16) handles (r0+l16, h)
    int isF32 = *flag;
    for (int r0 = beg; r0 < end; r0 += 16) {
        int rr = r0 + l16;
        if (rr < end) {
            float alpha = EX2[(size_t)rr * 4 + h] * invn;
            int e = eidx[rr];
            store_out(alpha_out, aoff + (size_t)e * 4 + h, alpha, isF32);
        }
    }
}

extern "C" void kernel_launch(void* const* d_in, const int* in_sizes, int n_in,
                              void* d_out, int out_size, void* d_ws, size_t ws_size,
                              hipStream_t stream) {
    const int* ei = (const int*)d_in[1];
    const int N  = in_sizes[0] / 16;
    const int E  = in_sizes[1] / 2;
    const int ET = E + N;
    const int NB = (N + 255) / 256;          // scan blocks

    // ---------------- workspace carve ------------------------------------
    float* P = (float*)d_ws;
    float* encW = P; P += 2048;  float* encb = P; P += 128;
    float* b1l  = P; P += 128;   float* b1r  = P; P += 128;
    float* att1 = P; P += 128;   float* bo1  = P; P += 128;
    float* b2l  = P; P += 128;   float* b2r  = P; P += 128;
    float* att2 = P; P += 128;   float* bo2  = P; P += 128;
    float* mb1  = P; P += 128;   float* mW2  = P; P += 128;
    float* mb2  = P; P += 4;
    int*  FLAG  = (int*)P; P += 4;
    int*  CNT   = (int*)P; P += N;
    int*  RS    = (int*)P; P += N + 1;
    int*  CUR   = (int*)P; P += N;
    int*  BSUM  = (int*)P; P += NB;
    int*  EIDX  = (int*)P; P += ET;
    int*  SRC   = (int*)P; P += ET;
    float* EX2  = P; P += (size_t)ET * 4;
    P = (float*)(((uintptr_t)P + 15) & ~(uintptr_t)15);   // 16B align
    __hip_bfloat16* W1Lt = (__hip_bfloat16*)P;            // 5 x 128*128 bf16
    __hip_bfloat16* W1Rt = W1Lt + 16384;
    __hip_bfloat16* W2Lt = W1Rt + 16384;
    __hip_bfloat16* W2Rt = W2Lt + 16384;
    __hip_bfloat16* MW1t = W2Rt + 16384;
    __hip_bfloat16* Hb   = MW1t + 16384;                  // N*128 bf16
    __hip_bfloat16* XL   = Hb + (size_t)N * 128;
    __hip_bfloat16* XR   = XL + (size_t)N * 128;

    // ---------------- dtype detect + fused param conversion ---------------
    k_detect<<<1, 256, 0, stream>>>((const unsigned short*)d_in[4], 2048, FLAG);

    CvtTab tab;
    const int srcIdx[NCVT] = {4, 5, 7, 9, 10, 11, 13, 15, 16, 17, 19, 20, 21};
    float* dsts[NCVT] = {encW, encb, b1l, b1r, att1, bo1, b2l, b2r, att2, bo2, mb1, mW2, mb2};
    const int ns[NCVT] = {2048, 128, 128, 128, 128, 128, 128, 128, 128, 128, 128, 128, 1};
    int tot = 0;
    for (int i = 0; i < NCVT; ++i) {
        tab.src[i] = d_in[srcIdx[i]];
        tab.dst[i] = dsts[i];
        tab.n[i] = ns[i];
        tot += ns[i];
    }
    tab.total = tot;
    k_cvt_all<<<(tot + 255) / 256, 256, 0, stream>>>(tab, FLAG);

    WtTab wt;
    wt.src[0] = d_in[6];  wt.dst[0] = W1Lt;
    wt.src[1] = d_in[8];  wt.dst[1] = W1Rt;
    wt.src[2] = d_in[12]; wt.dst[2] = W2Lt;
    wt.src[3] = d_in[14]; wt.dst[3] = W2Rt;
    wt.src[4] = d_in[18]; wt.dst[4] = MW1t;
    k_cvtWt_all<<<640, 128, 0, stream>>>(wt, FLAG);

    // ---------------- CSR by dst (parallel scan) --------------------------
    const int etGrid = (ET + 255) / 256;
    k_zero<<<NB, 256, 0, stream>>>(CNT, N);
    k_hist<<<etGrid, 256, 0, stream>>>(ei, E, N, CNT);
    k_scanA<<<NB, 256, 0, stream>>>(CNT, N, RS, BSUM);
    k_scanB<<<1, 1024, 0, stream>>>(BSUM, NB, RS, N);
    k_scanC<<<NB, 256, 0, stream>>>(RS, CUR, BSUM, N);
    k_fill<<<etGrid, 256, 0, stream>>>(ei, E, N, CUR, EIDX, SRC);

    const size_t a1_off = (size_t)N;
    const size_t a2_off = (size_t)N + (size_t)ET * 4;
    const int gGrid = (N + 63) / 64;
    const int fGrid = (N + 3) / 4;

    k_encoder<<<N, 128, 0, stream>>>(d_in[0], encW, encb, FLAG, Hb);

    // ---- GAT layer 1 ----
    k_gemm2_mfma<<<gGrid, 256, 0, stream>>>(Hb, W1Lt, b1l, W1Rt, b1r, N, XL, XR);
    k_gat_fused<<<fGrid, 256, 0, stream>>>(XL, XR, RS, SRC, EIDX, N, att1, bo1, 1,
                                           EX2, d_out, a1_off, FLAG, Hb);

    // ---- GAT layer 2 ----
    k_gemm2_mfma<<<gGrid, 256, 0, stream>>>(Hb, W2Lt, b2l, W2Rt, b2r, N, XL, XR);
    k_gat_fused<<<fGrid, 256, 0, stream>>>(XL, XR, RS, SRC, EIDX, N, att2, bo2, 0,
                                           EX2, d_out, a2_off, FLAG, Hb);

    k_mlp_mfma<<<gGrid, 256, 0, stream>>>(Hb, MW1t, mb1, mW2, mb2, N, d_out, FLAG);
}

// Round 10
// 433.849 us; speedup vs baseline: 28.4910x; 1.0414x over previous
//
#include <hip/hip_runtime.h>
#include <hip/hip_bf16.h>

#define NEG_SLOPE 0.2f
#define AS 136   // padded LDS row stride (bf16 elems): breaks 128-stride bank conflicts

typedef __bf16 bf16x8 __attribute__((ext_vector_type(8)));
typedef float  f32x4  __attribute__((ext_vector_type(4)));

__device__ __forceinline__ float b2f(__hip_bfloat16 v) { return __bfloat162float(v); }
__device__ __forceinline__ __hip_bfloat16 f2b(float v) { return __float2bfloat16(v); }
__device__ __forceinline__ float lo16(unsigned u) { return __uint_as_float(u << 16); }
__device__ __forceinline__ float hi16(unsigned u) { return __uint_as_float(u & 0xFFFF0000u); }

// ---- dtype detection (UNCHANGED — works; do not touch) --------------------
__global__ void k_detect(const unsigned short* __restrict__ w, int n, int* __restrict__ flag) {
    __shared__ int sh[256];
    int cnt = 0;
    for (int i = threadIdx.x * 2; i < n; i += 512) {   // even indices only
        int e = (w[i] >> 7) & 0xFF;
        if (e == 0 || e >= 0xC0) cnt++;
    }
    sh[threadIdx.x] = cnt;
    __syncthreads();
    for (int off = 128; off >= 1; off >>= 1) {
        if (threadIdx.x < off) sh[threadIdx.x] += sh[threadIdx.x + off];
        __syncthreads();
    }
    if (threadIdx.x == 0) *flag = (sh[0] > 128) ? 1 : 0;
}

// ---- fused conversion of all small fp tensors (one launch) ----------------
#define NCVT 13
struct CvtTab {
    const void* src[NCVT];
    float*      dst[NCVT];
    int         n[NCVT];
    int         total;
};
__global__ void k_cvt_all(CvtTab tab, const int* __restrict__ flag) {
    int i = blockIdx.x * blockDim.x + threadIdx.x;
    if (i >= tab.total) return;
    int seg = 0, rem = i;
    while (rem >= tab.n[seg]) { rem -= tab.n[seg]; ++seg; }
    float v = (*flag) ? ((const float*)tab.src[seg])[rem]
                      : b2f(((const __hip_bfloat16*)tab.src[seg])[rem]);
    tab.dst[seg][rem] = v;
}

// ---- fused convert+transpose of the 5 128x128 weights (one launch) --------
struct WtTab { const void* src[5]; __hip_bfloat16* dst[5]; };
__global__ void k_cvtWt_all(WtTab tab, const int* __restrict__ flag) {
    int m = blockIdx.x >> 7;           // 128 blocks per matrix
    int k = blockIdx.x & 127, c = threadIdx.x;
    float v = (*flag) ? ((const float*)tab.src[m])[k * 128 + c]
                      : b2f(((const __hip_bfloat16*)tab.src[m])[k * 128 + c]);
    tab.dst[m][c * 128 + k] = f2b(v);
}

__device__ __forceinline__ void store_out(void* out, size_t idx, float v, int isF32) {
    if (isF32) ((float*)out)[idx] = v;
    else       ((__hip_bfloat16*)out)[idx] = f2b(v);
}

// ---------------- CSR build (by dst), once per call -----------------------
__global__ void k_zero(int* __restrict__ p, int n) {
    int i = blockIdx.x * blockDim.x + threadIdx.x;
    if (i < n) p[i] = 0;
}

__global__ void k_hist(const int* __restrict__ ei, int E, int N, int* __restrict__ cnt) {
    int e = blockIdx.x * blockDim.x + threadIdx.x;
    if (e >= E + N) return;
    int d = (e < E) ? ei[E + e] : (e - E);
    if ((unsigned)d >= (unsigned)N) return;
    atomicAdd(&cnt[d], 1);
}

// ---- 3-phase parallel exclusive scan -------------------------------------
__global__ __launch_bounds__(256) void k_scanA(const int* __restrict__ cnt, int N,
                                               int* __restrict__ rs, int* __restrict__ bsum) {
    __shared__ int sh[256];
    int t = threadIdx.x, i = blockIdx.x * 256 + t;
    int v = (i < N) ? cnt[i] : 0;
    sh[t] = v;
    __syncthreads();
    for (int off = 1; off < 256; off <<= 1) {
        int u = (t >= off) ? sh[t - off] : 0;
        __syncthreads();
        sh[t] += u;
        __syncthreads();
    }
    if (i < N) rs[i] = sh[t] - v;                    // block-local exclusive
    if (t == 255) bsum[blockIdx.x] = sh[255];
}

__global__ __launch_bounds__(1024) void k_scanB(int* __restrict__ bsum, int B,
                                                int* __restrict__ rs, int N) {
    __shared__ int sh[1024];
    int t = threadIdx.x;
    int carry = 0;
    for (int base = 0; base < B; base += 1024) {
        int idx = base + t;
        int v = (idx < B) ? bsum[idx] : 0;
        sh[t] = v;
        __syncthreads();
        for (int off = 1; off < 1024; off <<= 1) {
            int u = (t >= off) ? sh[t - off] : 0;
            __syncthreads();
            sh[t] += u;
            __syncthreads();
        }
        if (idx < B) bsum[idx] = carry + sh[t] - v;  // global exclusive
        carry += sh[1023];
        __syncthreads();
    }
    if (t == 0) rs[N] = carry;                       // total
}

__global__ __launch_bounds__(256) void k_scanC(int* __restrict__ rs, int* __restrict__ cur,
                                               const int* __restrict__ bsum, int N) {
    int i = blockIdx.x * 256 + threadIdx.x;
    if (i >= N) return;
    int v = rs[i] + bsum[blockIdx.x];
    rs[i] = v;
    cur[i] = v;
}

__global__ void k_fill(const int* __restrict__ ei, int E, int N,
                       int* __restrict__ cur, int* __restrict__ eidx,
                       int* __restrict__ srcc) {
    int e = blockIdx.x * blockDim.x + threadIdx.x;
    if (e >= E + N) return;
    int s, d;
    if (e < E) { s = ei[e]; d = ei[E + e]; } else { s = d = e - E; }
    if ((unsigned)d >= (unsigned)N) return;
    int pos = atomicAdd(&cur[d], 1);
    eidx[pos] = e;
    srcc[pos] = s;
}

// ---------------- encoder: h = x @ enc_W + enc_b --------------------------
__global__ void k_encoder(const void* __restrict__ x, const float* __restrict__ W,
                          const float* __restrict__ b, const int* __restrict__ flag,
                          __hip_bfloat16* __restrict__ h) {
    int n = blockIdx.x, j = threadIdx.x;
    __shared__ float xs[16];
    if (j < 16)
        xs[j] = (*flag) ? ((const float*)x)[n * 16 + j]
                        : b2f(((const __hip_bfloat16*)x)[n * 16 + j]);
    __syncthreads();
    float acc = b[j];
#pragma unroll
    for (int k = 0; k < 16; ++k) acc += xs[k] * W[k * 128 + j];
    h[(size_t)n * 128 + j] = f2b(acc);
}

// --- dual MFMA GEMM: stage hA once, loop over {Wl->xl, Wr->xr} -------------
__global__ __launch_bounds__(256) void k_gemm2_mfma(
        const __hip_bfloat16* __restrict__ in,
        const __hip_bfloat16* __restrict__ WLt, const float* __restrict__ bl,
        const __hip_bfloat16* __restrict__ WRt, const float* __restrict__ br,
        int N, __hip_bfloat16* __restrict__ xl, __hip_bfloat16* __restrict__ xr) {
    __shared__ __hip_bfloat16 hA[64 * AS];
    __shared__ __hip_bfloat16 wB[128 * AS];
    int t = threadIdx.x, rbase = blockIdx.x * 64;
    for (int i = t; i < 1024; i += 256) {          // stage 64 h rows (16 KB) ONCE
        int r = i >> 4, seg = i & 15;
        int gr = rbase + r;
        uint4 v = {0u, 0u, 0u, 0u};
        if (gr < N) v = ((const uint4*)(in + (size_t)gr * 128))[seg];
        ((uint4*)(hA + r * AS))[seg] = v;
    }
    int wave = t >> 6, lane = t & 63, l16 = lane & 15, kq = lane >> 4;
#pragma unroll
    for (int pass = 0; pass < 2; ++pass) {
        const __hip_bfloat16* Wt = pass ? WRt : WLt;
        const float* bias        = pass ? br  : bl;
        __hip_bfloat16* out      = pass ? xr  : xl;
        __syncthreads();                           // wB free (and hA staged on pass 0)
        for (int i = t; i < 2048; i += 256) {      // stage Wt (32 KB)
            int c = i >> 4, seg = i & 15;
            ((uint4*)(wB + c * AS))[seg] = ((const uint4*)(Wt + c * 128))[seg];
        }
        __syncthreads();
        f32x4 acc[8];
#pragma unroll
        for (int i = 0; i < 8; ++i) acc[i] = (f32x4){0.f, 0.f, 0.f, 0.f};
#pragma unroll
        for (int ks = 0; ks < 4; ++ks) {
            int kofs = ks * 32 + kq * 8;
            bf16x8 a = *(const bf16x8*)(hA + (wave * 16 + l16) * AS + kofs);
#pragma unroll
            for (int cb = 0; cb < 8; ++cb) {
                bf16x8 b = *(const bf16x8*)(wB + (cb * 16 + l16) * AS + kofs);
                acc[cb] = __builtin_amdgcn_mfma_f32_16x16x32_bf16(a, b, acc[cb], 0, 0, 0);
            }
        }
#pragma unroll
        for (int cb = 0; cb < 8; ++cb) {
            int c = cb * 16 + l16;
            float bc = bias[c];
#pragma unroll
            for (int i = 0; i < 4; ++i) {
                int r = rbase + wave * 16 + kq * 4 + i;
                if (r < N) out[(size_t)r * 128 + c] = f2b(acc[cb][i] + bc);
            }
        }
    }
}

// --------- MFMA MLP head: sigmoid(relu(h2@W1+b1)@W2 + b2), fused ----------
__global__ __launch_bounds__(256) void k_mlp_mfma(
        const __hip_bfloat16* __restrict__ h2, const __hip_bfloat16* __restrict__ W1t,
        const float* __restrict__ b1, const float* __restrict__ W2,
        const float* __restrict__ b2, int N,
        void* __restrict__ d_out, const int* __restrict__ flag) {
    __shared__ __hip_bfloat16 hA[64 * AS];
    __shared__ __hip_bfloat16 wB[128 * AS];
    int t = threadIdx.x, rbase = blockIdx.x * 64;
    for (int i = t; i < 2048; i += 256) {
        int c = i >> 4, seg = i & 15;
        ((uint4*)(wB + c * AS))[seg] = ((const uint4*)(W1t + c * 128))[seg];
    }
    for (int i = t; i < 1024; i += 256) {
        int r = i >> 4, seg = i & 15;
        int gr = rbase + r;
        uint4 v = {0u, 0u, 0u, 0u};
        if (gr < N) v = ((const uint4*)(h2 + (size_t)gr * 128))[seg];
        ((uint4*)(hA + r * AS))[seg] = v;
    }
    __syncthreads();
    int wave = t >> 6, lane = t & 63, l16 = lane & 15, kq = lane >> 4;
    f32x4 acc[8];
#pragma unroll
    for (int i = 0; i < 8; ++i) acc[i] = (f32x4){0.f, 0.f, 0.f, 0.f};
#pragma unroll
    for (int ks = 0; ks < 4; ++ks) {
        int kofs = ks * 32 + kq * 8;
        bf16x8 a = *(const bf16x8*)(hA + (wave * 16 + l16) * AS + kofs);
#pragma unroll
        for (int cb = 0; cb < 8; ++cb) {
            bf16x8 b = *(const bf16x8*)(wB + (cb * 16 + l16) * AS + kofs);
            acc[cb] = __builtin_amdgcn_mfma_f32_16x16x32_bf16(a, b, acc[cb], 0, 0, 0);
        }
    }
    float p[4] = {0.f, 0.f, 0.f, 0.f};
#pragma unroll
    for (int cb = 0; cb < 8; ++cb) {
        int c = cb * 16 + l16;
        float bb = b1[c], w = W2[c];
#pragma unroll
        for (int i = 0; i < 4; ++i) p[i] += fmaxf(acc[cb][i] + bb, 0.f) * w;
    }
#pragma unroll
    for (int i = 0; i < 4; ++i) {
        p[i] += __shfl_xor(p[i], 8, 16);
        p[i] += __shfl_xor(p[i], 4, 16);
        p[i] += __shfl_xor(p[i], 2, 16);
        p[i] += __shfl_xor(p[i], 1, 16);
    }
    if (l16 == 0) {
        int isF32 = *flag;
        float bb = b2[0];
#pragma unroll
        for (int i = 0; i < 4; ++i) {
            int r = rbase + wave * 16 + kq * 4 + i;
            if (r < N)
                store_out(d_out, (size_t)r,
                          1.f / (1.f + __expf(-(p[i] + bb))), isF32);
        }
    }
}

// ===== fused GAT edge pipeline: one wave per dst, 8-way + masked tail =====
__device__ __forceinline__ float edge_p(unsigned u, float xr0, float xr1,
                                        float a0, float a1) {
    float v0 = lo16(u) + xr0; v0 = fmaxf(v0, 0.f) + NEG_SLOPE * fminf(v0, 0.f);
    float v1 = hi16(u) + xr1; v1 = fmaxf(v1, 0.f) + NEG_SLOPE * fminf(v1, 0.f);
    return v0 * a0 + v1 * a1;
}

__global__ __launch_bounds__(256) void k_gat_fused(
        const __hip_bfloat16* __restrict__ xl,
        const __hip_bfloat16* __restrict__ xr,
        const int* __restrict__ rs, const int* __restrict__ srcc,
        const int* __restrict__ eidx, int N,
        const float* __restrict__ att, const float* __restrict__ bo, int relu,
        float* __restrict__ EX2,
        void* __restrict__ alpha_out, size_t aoff, const int* __restrict__ flag,
        __hip_bfloat16* __restrict__ hout) {
    int wv = threadIdx.x >> 6, lane = threadIdx.x & 63;
    int n = blockIdx.x * 4 + wv;
    if (n >= N) return;
    int h = lane >> 4, l16 = lane & 15, c0 = lane * 2;
    unsigned uxr = ((const unsigned*)(xr + (size_t)n * 128))[lane];
    float xr0 = lo16(uxr), xr1 = hi16(uxr);
    float a0 = att[c0], a1 = att[c0 + 1];
    int beg = rs[n], end = rs[n + 1];
    float den = 0.f, acc0 = 0.f, acc1 = 0.f;
    int r = beg;
    // full 8-wide iterations (no per-edge masking)
    for (; r + 8 <= end; r += 8) {
        unsigned u[8];
#pragma unroll
        for (int j = 0; j < 8; ++j) {
            unsigned s = min((unsigned)srcc[r + j], (unsigned)(N - 1));
            u[j] = ((const unsigned*)(xl + (size_t)s * 128))[lane];
        }
        float p[8];
#pragma unroll
        for (int j = 0; j < 8; ++j) p[j] = edge_p(u[j], xr0, xr1, a0, a1);
#pragma unroll
        for (int st = 1; st < 16; st <<= 1) {
#pragma unroll
            for (int j = 0; j < 8; ++j) p[j] += __shfl_xor(p[j], st, 16);
        }
        float ex[8];
#pragma unroll
        for (int j = 0; j < 8; ++j) ex[j] = __expf(fminf(fmaxf(p[j], -30.f), 30.f));
        if (l16 == 0) {
#pragma unroll
            for (int j = 0; j < 8; ++j) EX2[(size_t)(r + j) * 4 + h] = ex[j];
        }
#pragma unroll
        for (int j = 0; j < 8; ++j) {
            den  += ex[j];
            acc0 += ex[j] * lo16(u[j]);
            acc1 += ex[j] * hi16(u[j]);
        }
    }
    // one masked 8-wide iteration for the tail (1..7 edges)
    if (r < end) {
        unsigned u[8];
#pragma unroll
        for (int j = 0; j < 8; ++j) {
            int rr = (r + j < end) ? (r + j) : (end - 1);
            unsigned s = min((unsigned)srcc[rr], (unsigned)(N - 1));
            u[j] = ((const unsigned*)(xl + (size_t)s * 128))[lane];
        }
        float p[8];
#pragma unroll
        for (int j = 0; j < 8; ++j) p[j] = edge_p(u[j], xr0, xr1, a0, a1);
#pragma unroll
        for (int st = 1; st < 16; st <<= 1) {
#pragma unroll
            for (int j = 0; j < 8; ++j) p[j] += __shfl_xor(p[j], st, 16);
        }
        float ex[8];
#pragma unroll
        for (int j = 0; j < 8; ++j) {
            ex[j] = (r + j < end) ? __expf(fminf(fmaxf(p[j], -30.f), 30.f)) : 0.f;
        }
        if (l16 == 0) {
#pragma unroll
            for (int j = 0; j < 8; ++j)
                if (r + j < end) EX2[(size_t)(r + j) * 4 + h] = ex[j];
        }
#pragma unroll
        for (int j = 0; j < 8; ++j) {
            den  += ex[j];
            acc0 += ex[j] * lo16(u[j]);
            acc1 += ex[j] * hi16(u[j]);
        }
    }
    float invn = 1.f / fmaxf(den, 1e-30f);
    float v0 = acc0 * invn + bo[c0], v1 = acc1 * invn + bo[c0 + 1];
    if (relu) { v0 = fmaxf(v0, 0.f); v1 = fmaxf(v1, 0.f); }
    __hip_bfloat16 h0 = f2b(v0), h1 = f2b(v1);
    ushort2 st;
    st.x = *(unsigned short*)&h0;
    st.y = *(unsigned short*)&h1;
    ((ushort2*)(hout + (size_t)n * 128))[lane] = st;
    // alpha outputs: 16 edges in parallel, lane (h,l16) handles (r0+l16, h)
    int isF32 = *flag;
    for (int r0 = beg; r0 < end; r0 += 16) {
        int rr = r0 + l16;
        if (rr < end) {
            float alpha = EX2[(size_t)rr * 4 + h] * invn;
            int e = eidx[rr];
            store_out(alpha_out, aoff + (size_t)e * 4 + h, alpha, isF32);
        }
    }
}

extern "C" void kernel_launch(void* const* d_in, const int* in_sizes, int n_in,
                              void* d_out, int out_size, void* d_ws, size_t ws_size,
                              hipStream_t stream) {
    const int* ei = (const int*)d_in[1];
    const int N  = in_sizes[0] / 16;
    const int E  = in_sizes[1] / 2;
    const int ET = E + N;
    const int NB = (N + 255) / 256;          // scan blocks

    // ---------------- workspace carve ------------------------------------
    float* P = (float*)d_ws;
    float* encW = P; P += 2048;  float* encb = P; P += 128;
    float* b1l  = P; P += 128;   float* b1r  = P; P += 128;
    float* att1 = P; P += 128;   float* bo1  = P; P += 128;
    float* b2l  = P; P += 128;   float* b2r  = P; P += 128;
    float* att2 = P; P += 128;   float* bo2  = P; P += 128;
    float* mb1  = P; P += 128;   float* mW2  = P; P += 128;
    float* mb2  = P; P += 4;
    int*  FLAG  = (int*)P; P += 4;
    int*  CNT   = (int*)P; P += N;
    int*  RS    = (int*)P; P += N + 1;
    int*  CUR   = (int*)P; P += N;
    int*  BSUM  = (int*)P; P += NB;
    int*  EIDX  = (int*)P; P += ET;
    int*  SRC   = (int*)P; P += ET;
    float* EX2  = P; P += (size_t)ET * 4;
    P = (float*)(((uintptr_t)P + 15) & ~(uintptr_t)15);   // 16B align
    __hip_bfloat16* W1Lt = (__hip_bfloat16*)P;            // 5 x 128*128 bf16
    __hip_bfloat16* W1Rt = W1Lt + 16384;
    __hip_bfloat16* W2Lt = W1Rt + 16384;
    __hip_bfloat16* W2Rt = W2Lt + 16384;
    __hip_bfloat16* MW1t = W2Rt + 16384;
    __hip_bfloat16* Hb   = MW1t + 16384;                  // N*128 bf16
    __hip_bfloat16* XL   = Hb + (size_t)N * 128;
    __hip_bfloat16* XR   = XL + (size_t)N * 128;

    // ---------------- dtype detect + fused param conversion ---------------
    k_detect<<<1, 256, 0, stream>>>((const unsigned short*)d_in[4], 2048, FLAG);

    CvtTab tab;
    const int srcIdx[NCVT] = {4, 5, 7, 9, 10, 11, 13, 15, 16, 17, 19, 20, 21};
    float* dsts[NCVT] = {encW, encb, b1l, b1r, att1, bo1, b2l, b2r, att2, bo2, mb1, mW2, mb2};
    const int ns[NCVT] = {2048, 128, 128, 128, 128, 128, 128, 128, 128, 128, 128, 128, 1};
    int tot = 0;
    for (int i = 0; i < NCVT; ++i) {
        tab.src[i] = d_in[srcIdx[i]];
        tab.dst[i] = dsts[i];
        tab.n[i] = ns[i];
        tot += ns[i];
    }
    tab.total = tot;
    k_cvt_all<<<(tot + 255) / 256, 256, 0, stream>>>(tab, FLAG);

    WtTab wt;
    wt.src[0] = d_in[6];  wt.dst[0] = W1Lt;
    wt.src[1] = d_in[8];  wt.dst[1] = W1Rt;
    wt.src[2] = d_in[12]; wt.dst[2] = W2Lt;
    wt.src[3] = d_in[14]; wt.dst[3] = W2Rt;
    wt.src[4] = d_in[18]; wt.dst[4] = MW1t;
    k_cvtWt_all<<<640, 128, 0, stream>>>(wt, FLAG);

    // ---------------- CSR by dst (parallel scan) --------------------------
    const int etGrid = (ET + 255) / 256;
    k_zero<<<NB, 256, 0, stream>>>(CNT, N);
    k_hist<<<etGrid, 256, 0, stream>>>(ei, E, N, CNT);
    k_scanA<<<NB, 256, 0, stream>>>(CNT, N, RS, BSUM);
    k_scanB<<<1, 1024, 0, stream>>>(BSUM, NB, RS, N);
    k_scanC<<<NB, 256, 0, stream>>>(RS, CUR, BSUM, N);
    k_fill<<<etGrid, 256, 0, stream>>>(ei, E, N, CUR, EIDX, SRC);

    const size_t a1_off = (size_t)N;
    const size_t a2_off = (size_t)N + (size_t)ET * 4;
    const int gGrid = (N + 63) / 64;
    const int fGrid = (N + 3) / 4;

    k_encoder<<<N, 128, 0, stream>>>(d_in[0], encW, encb, FLAG, Hb);

    // ---- GAT layer 1 ----
    k_gemm2_mfma<<<gGrid, 256, 0, stream>>>(Hb, W1Lt, b1l, W1Rt, b1r, N, XL, XR);
    k_gat_fused<<<fGrid, 256, 0, stream>>>(XL, XR, RS, SRC, EIDX, N, att1, bo1, 1,
                                           EX2, d_out, a1_off, FLAG, Hb);

    // ---- GAT layer 2 ----
    k_gemm2_mfma<<<gGrid, 256, 0, stream>>>(Hb, W2Lt, b2l, W2Rt, b2r, N, XL, XR);
    k_gat_fused<<<fGrid, 256, 0, stream>>>(XL, XR, RS, SRC, EIDX, N, att2, bo2, 0,
                                           EX2, d_out, a2_off, FLAG, Hb);

    k_mlp_mfma<<<gGrid, 256, 0, stream>>>(Hb, MW1t, mb1, mW2, mb2, N, d_out, FLAG);
}

// Round 11
// 411.329 us; speedup vs baseline: 30.0509x; 1.0547x over previous
//
#include <hip/hip_runtime.h>
#include <hip/hip_bf16.h>

#define NEG_SLOPE 0.2f
#define AS 136   // padded LDS row stride (bf16 elems): breaks 128-stride bank conflicts
#define CAPD 64  // per-wave LDS ex cache depth (edges per dst); overflow -> global EX2

typedef __bf16 bf16x8 __attribute__((ext_vector_type(8)));
typedef float  f32x4  __attribute__((ext_vector_type(4)));

__device__ __forceinline__ float b2f(__hip_bfloat16 v) { return __bfloat162float(v); }
__device__ __forceinline__ __hip_bfloat16 f2b(float v) { return __float2bfloat16(v); }
__device__ __forceinline__ float lo16(unsigned u) { return __uint_as_float(u << 16); }
__device__ __forceinline__ float hi16(unsigned u) { return __uint_as_float(u & 0xFFFF0000u); }

// wild-exponent test for one bf16-viewed ushort (even index of suspected fp32)
__device__ __forceinline__ int wild16(unsigned short w) {
    int e = (w >> 7) & 0xFF;
    return (e == 0 || e >= 0xC0) ? 1 : 0;
}

__device__ __forceinline__ void store_out(void* out, size_t idx, float v, int isF32) {
    if (isF32) ((float*)out)[idx] = v;
    else       ((__hip_bfloat16*)out)[idx] = f2b(v);
}

// ---- fused conversion of all small fp tensors + FLAG publish (one launch) --
#define NCVT 13
struct CvtTab {
    const void* src[NCVT];
    float*      dst[NCVT];
    int         n[NCVT];
    int         total;
};
// block-local dtype detection on det[] (enc_W), 1024 even samples / 256 thr
__global__ void k_cvt_all(CvtTab tab, const unsigned short* __restrict__ det,
                          int* __restrict__ FLAG) {
    __shared__ int sh[256];
    int t = threadIdx.x;
    int cnt = 0;
#pragma unroll
    for (int j = 0; j < 4; ++j) cnt += wild16(det[t * 8 + j * 2]);
    sh[t] = cnt;
    __syncthreads();
    for (int off = 128; off >= 1; off >>= 1) {
        if (t < off) sh[t] += sh[t + off];
        __syncthreads();
    }
    int isF32 = sh[0] > 128;
    if (blockIdx.x == 0 && t == 0) *FLAG = isF32;
    int i = blockIdx.x * blockDim.x + t;
    if (i >= tab.total) return;
    int seg = 0, rem = i;
    while (rem >= tab.n[seg]) { rem -= tab.n[seg]; ++seg; }
    float v = isF32 ? ((const float*)tab.src[seg])[rem]
                    : b2f(((const __hip_bfloat16*)tab.src[seg])[rem]);
    tab.dst[seg][rem] = v;
}

// ---- fused convert+transpose of the 5 128x128 weights (one launch) --------
struct WtTab { const void* src[5]; __hip_bfloat16* dst[5]; };
__global__ void k_cvtWt_all(WtTab tab, const unsigned short* __restrict__ det) {
    __shared__ int sh[128];
    int t = threadIdx.x;
    int cnt = 0;
#pragma unroll
    for (int j = 0; j < 8; ++j) cnt += wild16(det[t * 16 + j * 2]);
    sh[t] = cnt;
    __syncthreads();
    for (int off = 64; off >= 1; off >>= 1) {
        if (t < off) sh[t] += sh[t + off];
        __syncthreads();
    }
    int isF32 = sh[0] > 128;
    int m = blockIdx.x >> 7;           // 128 blocks per matrix
    int k = blockIdx.x & 127, c = t;
    float v = isF32 ? ((const float*)tab.src[m])[k * 128 + c]
                    : b2f(((const __hip_bfloat16*)tab.src[m])[k * 128 + c]);
    tab.dst[m][c * 128 + k] = f2b(v);
}

// ---------------- CSR build (by dst), once per call -----------------------
__global__ void k_zero(int* __restrict__ p, int n) {
    int i = blockIdx.x * blockDim.x + threadIdx.x;
    if (i < n) p[i] = 0;
}

__global__ void k_hist(const int* __restrict__ ei, int E, int N, int* __restrict__ cnt) {
    int e = blockIdx.x * blockDim.x + threadIdx.x;
    if (e >= E + N) return;
    int d = (e < E) ? ei[E + e] : (e - E);
    if ((unsigned)d >= (unsigned)N) return;
    atomicAdd(&cnt[d], 1);
}

// ---- 3-phase parallel exclusive scan -------------------------------------
__global__ __launch_bounds__(256) void k_scanA(const int* __restrict__ cnt, int N,
                                               int* __restrict__ rs, int* __restrict__ bsum) {
    __shared__ int sh[256];
    int t = threadIdx.x, i = blockIdx.x * 256 + t;
    int v = (i < N) ? cnt[i] : 0;
    sh[t] = v;
    __syncthreads();
    for (int off = 1; off < 256; off <<= 1) {
        int u = (t >= off) ? sh[t - off] : 0;
        __syncthreads();
        sh[t] += u;
        __syncthreads();
    }
    if (i < N) rs[i] = sh[t] - v;                    // block-local exclusive
    if (t == 255) bsum[blockIdx.x] = sh[255];
}

__global__ __launch_bounds__(1024) void k_scanB(int* __restrict__ bsum, int B,
                                                int* __restrict__ rs, int N) {
    __shared__ int sh[1024];
    int t = threadIdx.x;
    int carry = 0;
    for (int base = 0; base < B; base += 1024) {
        int idx = base + t;
        int v = (idx < B) ? bsum[idx] : 0;
        sh[t] = v;
        __syncthreads();
        for (int off = 1; off < 1024; off <<= 1) {
            int u = (t >= off) ? sh[t - off] : 0;
            __syncthreads();
            sh[t] += u;
            __syncthreads();
        }
        if (idx < B) bsum[idx] = carry + sh[t] - v;  // global exclusive
        carry += sh[1023];
        __syncthreads();
    }
    if (t == 0) rs[N] = carry;                       // total
}

__global__ __launch_bounds__(256) void k_scanC(int* __restrict__ rs, int* __restrict__ cur,
                                               const int* __restrict__ bsum, int N) {
    int i = blockIdx.x * 256 + threadIdx.x;
    if (i >= N) return;
    int v = rs[i] + bsum[blockIdx.x];
    rs[i] = v;
    cur[i] = v;
}

__global__ void k_fill(const int* __restrict__ ei, int E, int N,
                       int* __restrict__ cur, int* __restrict__ eidx,
                       int* __restrict__ srcc) {
    int e = blockIdx.x * blockDim.x + threadIdx.x;
    if (e >= E + N) return;
    int s, d;
    if (e < E) { s = ei[e]; d = ei[E + e]; } else { s = d = e - E; }
    if ((unsigned)d >= (unsigned)N) return;
    int pos = atomicAdd(&cur[d], 1);
    eidx[pos] = e;
    srcc[pos] = s;
}

// --- layer-1: fused encoder + dual MFMA GEMM ------------------------------
// h = x@encW+encb computed straight into hA (LDS), then {Wl->xl, Wr->xr}.
__global__ __launch_bounds__(256) void k_gemm2enc_mfma(
        const void* __restrict__ x, const float* __restrict__ encW,
        const float* __restrict__ encb, const int* __restrict__ flag,
        const __hip_bfloat16* __restrict__ WLt, const float* __restrict__ bl,
        const __hip_bfloat16* __restrict__ WRt, const float* __restrict__ br,
        int N, __hip_bfloat16* __restrict__ xl, __hip_bfloat16* __restrict__ xr) {
    __shared__ __hip_bfloat16 hA[64 * AS];
    __shared__ __hip_bfloat16 wB[128 * AS];
    float* encWs = (float*)wB;            // 2048 f32 (8 KB), aliased into wB
    float* xs    = encWs + 2048;          // 64*17 f32 (4.4 KB)
    int t = threadIdx.x, rbase = blockIdx.x * 64;
    int isF32 = *flag;
    for (int i = t; i < 2048; i += 256) encWs[i] = encW[i];
    for (int i = t; i < 1024; i += 256) {
        int r = i >> 4, k = i & 15, gr = rbase + r;
        float v = 0.f;
        if (gr < N)
            v = isF32 ? ((const float*)x)[(size_t)gr * 16 + k]
                      : b2f(((const __hip_bfloat16*)x)[(size_t)gr * 16 + k]);
        xs[r * 17 + k] = v;
    }
    __syncthreads();
    {   // each thread: row r = t>>2, cols c = (t&3) + cc*4  (bank-spread)
        int r = t >> 2, q = t & 3;
        float xv[16];
#pragma unroll
        for (int k = 0; k < 16; ++k) xv[k] = xs[r * 17 + k];
#pragma unroll
        for (int cc = 0; cc < 32; ++cc) {
            int c = q + cc * 4;
            float acc = encb[c];
#pragma unroll
            for (int k = 0; k < 16; ++k) acc += xv[k] * encWs[k * 128 + c];
            hA[r * AS + c] = f2b(acc);
        }
    }
    int wave = t >> 6, lane = t & 63, l16 = lane & 15, kq = lane >> 4;
#pragma unroll
    for (int pass = 0; pass < 2; ++pass) {
        const __hip_bfloat16* Wt = pass ? WRt : WLt;
        const float* bias        = pass ? br  : bl;
        __hip_bfloat16* out      = pass ? xr  : xl;
        __syncthreads();                           // hA done / wB free
        for (int i = t; i < 2048; i += 256) {      // stage Wt (32 KB)
            int c = i >> 4, seg = i & 15;
            ((uint4*)(wB + c * AS))[seg] = ((const uint4*)(Wt + c * 128))[seg];
        }
        __syncthreads();
        f32x4 acc[8];
#pragma unroll
        for (int i = 0; i < 8; ++i) acc[i] = (f32x4){0.f, 0.f, 0.f, 0.f};
#pragma unroll
        for (int ks = 0; ks < 4; ++ks) {
            int kofs = ks * 32 + kq * 8;
            bf16x8 a = *(const bf16x8*)(hA + (wave * 16 + l16) * AS + kofs);
#pragma unroll
            for (int cb = 0; cb < 8; ++cb) {
                bf16x8 b = *(const bf16x8*)(wB + (cb * 16 + l16) * AS + kofs);
                acc[cb] = __builtin_amdgcn_mfma_f32_16x16x32_bf16(a, b, acc[cb], 0, 0, 0);
            }
        }
#pragma unroll
        for (int cb = 0; cb < 8; ++cb) {
            int c = cb * 16 + l16;
            float bc = bias[c];
#pragma unroll
            for (int i = 0; i < 4; ++i) {
                int r = rbase + wave * 16 + kq * 4 + i;
                if (r < N) out[(size_t)r * 128 + c] = f2b(acc[cb][i] + bc);
            }
        }
    }
}

// --- dual MFMA GEMM: stage hA once, loop over {Wl->xl, Wr->xr} -------------
__global__ __launch_bounds__(256) void k_gemm2_mfma(
        const __hip_bfloat16* __restrict__ in,
        const __hip_bfloat16* __restrict__ WLt, const float* __restrict__ bl,
        const __hip_bfloat16* __restrict__ WRt, const float* __restrict__ br,
        int N, __hip_bfloat16* __restrict__ xl, __hip_bfloat16* __restrict__ xr) {
    __shared__ __hip_bfloat16 hA[64 * AS];
    __shared__ __hip_bfloat16 wB[128 * AS];
    int t = threadIdx.x, rbase = blockIdx.x * 64;
    for (int i = t; i < 1024; i += 256) {          // stage 64 h rows (16 KB) ONCE
        int r = i >> 4, seg = i & 15;
        int gr = rbase + r;
        uint4 v = {0u, 0u, 0u, 0u};
        if (gr < N) v = ((const uint4*)(in + (size_t)gr * 128))[seg];
        ((uint4*)(hA + r * AS))[seg] = v;
    }
    int wave = t >> 6, lane = t & 63, l16 = lane & 15, kq = lane >> 4;
#pragma unroll
    for (int pass = 0; pass < 2; ++pass) {
        const __hip_bfloat16* Wt = pass ? WRt : WLt;
        const float* bias        = pass ? br  : bl;
        __hip_bfloat16* out      = pass ? xr  : xl;
        __syncthreads();
        for (int i = t; i < 2048; i += 256) {      // stage Wt (32 KB)
            int c = i >> 4, seg = i & 15;
            ((uint4*)(wB + c * AS))[seg] = ((const uint4*)(Wt + c * 128))[seg];
        }
        __syncthreads();
        f32x4 acc[8];
#pragma unroll
        for (int i = 0; i < 8; ++i) acc[i] = (f32x4){0.f, 0.f, 0.f, 0.f};
#pragma unroll
        for (int ks = 0; ks < 4; ++ks) {
            int kofs = ks * 32 + kq * 8;
            bf16x8 a = *(const bf16x8*)(hA + (wave * 16 + l16) * AS + kofs);
#pragma unroll
            for (int cb = 0; cb < 8; ++cb) {
                bf16x8 b = *(const bf16x8*)(wB + (cb * 16 + l16) * AS + kofs);
                acc[cb] = __builtin_amdgcn_mfma_f32_16x16x32_bf16(a, b, acc[cb], 0, 0, 0);
            }
        }
#pragma unroll
        for (int cb = 0; cb < 8; ++cb) {
            int c = cb * 16 + l16;
            float bc = bias[c];
#pragma unroll
            for (int i = 0; i < 4; ++i) {
                int r = rbase + wave * 16 + kq * 4 + i;
                if (r < N) out[(size_t)r * 128 + c] = f2b(acc[cb][i] + bc);
            }
        }
    }
}

// --------- MFMA MLP head: sigmoid(relu(h2@W1+b1)@W2 + b2), fused ----------
__global__ __launch_bounds__(256) void k_mlp_mfma(
        const __hip_bfloat16* __restrict__ h2, const __hip_bfloat16* __restrict__ W1t,
        const float* __restrict__ b1, const float* __restrict__ W2,
        const float* __restrict__ b2, int N,
        void* __restrict__ d_out, const int* __restrict__ flag) {
    __shared__ __hip_bfloat16 hA[64 * AS];
    __shared__ __hip_bfloat16 wB[128 * AS];
    int t = threadIdx.x, rbase = blockIdx.x * 64;
    for (int i = t; i < 2048; i += 256) {
        int c = i >> 4, seg = i & 15;
        ((uint4*)(wB + c * AS))[seg] = ((const uint4*)(W1t + c * 128))[seg];
    }
    for (int i = t; i < 1024; i += 256) {
        int r = i >> 4, seg = i & 15;
        int gr = rbase + r;
        uint4 v = {0u, 0u, 0u, 0u};
        if (gr < N) v = ((const uint4*)(h2 + (size_t)gr * 128))[seg];
        ((uint4*)(hA + r * AS))[seg] = v;
    }
    __syncthreads();
    int wave = t >> 6, lane = t & 63, l16 = lane & 15, kq = lane >> 4;
    f32x4 acc[8];
#pragma unroll
    for (int i = 0; i < 8; ++i) acc[i] = (f32x4){0.f, 0.f, 0.f, 0.f};
#pragma unroll
    for (int ks = 0; ks < 4; ++ks) {
        int kofs = ks * 32 + kq * 8;
        bf16x8 a = *(const bf16x8*)(hA + (wave * 16 + l16) * AS + kofs);
#pragma unroll
        for (int cb = 0; cb < 8; ++cb) {
            bf16x8 b = *(const bf16x8*)(wB + (cb * 16 + l16) * AS + kofs);
            acc[cb] = __builtin_amdgcn_mfma_f32_16x16x32_bf16(a, b, acc[cb], 0, 0, 0);
        }
    }
    float p[4] = {0.f, 0.f, 0.f, 0.f};
#pragma unroll
    for (int cb = 0; cb < 8; ++cb) {
        int c = cb * 16 + l16;
        float bb = b1[c], w = W2[c];
#pragma unroll
        for (int i = 0; i < 4; ++i) p[i] += fmaxf(acc[cb][i] + bb, 0.f) * w;
    }
#pragma unroll
    for (int i = 0; i < 4; ++i) {
        p[i] += __shfl_xor(p[i], 8, 16);
        p[i] += __shfl_xor(p[i], 4, 16);
        p[i] += __shfl_xor(p[i], 2, 16);
        p[i] += __shfl_xor(p[i], 1, 16);
    }
    if (l16 == 0) {
        int isF32 = *flag;
        float bb = b2[0];
#pragma unroll
        for (int i = 0; i < 4; ++i) {
            int r = rbase + wave * 16 + kq * 4 + i;
            if (r < N)
                store_out(d_out, (size_t)r,
                          1.f / (1.f + __expf(-(p[i] + bb))), isF32);
        }
    }
}

// ===== fused GAT edge pipeline: one wave per dst, 8-way, LDS ex cache =====
__device__ __forceinline__ float edge_p(unsigned u, float xr0, float xr1,
                                        float a0, float a1) {
    float v0 = lo16(u) + xr0; v0 = fmaxf(v0, NEG_SLOPE * v0);   // leaky, 2 ops
    float v1 = hi16(u) + xr1; v1 = fmaxf(v1, NEG_SLOPE * v1);
    return v0 * a0 + v1 * a1;
}

__global__ __launch_bounds__(256) void k_gat_fused(
        const __hip_bfloat16* __restrict__ xl,
        const __hip_bfloat16* __restrict__ xr,
        const int* __restrict__ rs, const int* __restrict__ srcc,
        const int* __restrict__ eidx, int N,
        const float* __restrict__ att, const float* __restrict__ bo, int relu,
        float* __restrict__ EX2,
        void* __restrict__ alpha_out, size_t aoff, const int* __restrict__ flag,
        __hip_bfloat16* __restrict__ hout) {
    __shared__ float exsh[4][CAPD * 4];     // per-wave ex cache (4 KB)
    int wv = threadIdx.x >> 6, lane = threadIdx.x & 63;
    int n = blockIdx.x * 4 + wv;
    if (n >= N) return;
    int h = lane >> 4, l16 = lane & 15, c0 = lane * 2;
    unsigned uxr = ((const unsigned*)(xr + (size_t)n * 128))[lane];
    float xr0 = lo16(uxr), xr1 = hi16(uxr);
    float a0 = att[c0], a1 = att[c0 + 1];
    int beg = rs[n], end = rs[n + 1];
    float den = 0.f, acc0 = 0.f, acc1 = 0.f;
    int r = beg;
    for (; r + 8 <= end; r += 8) {                 // 8 independent edges in flight
        unsigned u[8];
#pragma unroll
        for (int j = 0; j < 8; ++j) {
            unsigned s = min((unsigned)srcc[r + j], (unsigned)(N - 1));
            u[j] = ((const unsigned*)(xl + (size_t)s * 128))[lane];
        }
        float p[8];
#pragma unroll
        for (int j = 0; j < 8; ++j) p[j] = edge_p(u[j], xr0, xr1, a0, a1);
#pragma unroll
        for (int st = 1; st < 16; st <<= 1) {
#pragma unroll
            for (int j = 0; j < 8; ++j) p[j] += __shfl_xor(p[j], st, 16);
        }
        float ex[8];
#pragma unroll
        for (int j = 0; j < 8; ++j) ex[j] = __expf(fminf(fmaxf(p[j], -30.f), 30.f));
        if (l16 == 0) {
#pragma unroll
            for (int j = 0; j < 8; ++j) {
                int idx = r + j - beg;
                if (idx < CAPD) exsh[wv][idx * 4 + h] = ex[j];
                else            EX2[(size_t)(r + j) * 4 + h] = ex[j];
            }
        }
#pragma unroll
        for (int j = 0; j < 8; ++j) {
            den  += ex[j];
            acc0 += ex[j] * lo16(u[j]);
            acc1 += ex[j] * hi16(u[j]);
        }
    }
    if (r < end) {                                 // masked tail (1..7 edges)
        unsigned u[8];
#pragma unroll
        for (int j = 0; j < 8; ++j) {
            int rr = (r + j < end) ? (r + j) : (end - 1);
            unsigned s = min((unsigned)srcc[rr], (unsigned)(N - 1));
            u[j] = ((const unsigned*)(xl + (size_t)s * 128))[lane];
        }
        float p[8];
#pragma unroll
        for (int j = 0; j < 8; ++j) p[j] = edge_p(u[j], xr0, xr1, a0, a1);
#pragma unroll
        for (int st = 1; st < 16; st <<= 1) {
#pragma unroll
            for (int j = 0; j < 8; ++j) p[j] += __shfl_xor(p[j], st, 16);
        }
        float ex[8];
#pragma unroll
        for (int j = 0; j < 8; ++j)
            ex[j] = (r + j < end) ? __expf(fminf(fmaxf(p[j], -30.f), 30.f)) : 0.f;
        if (l16 == 0) {
#pragma unroll
            for (int j = 0; j < 8; ++j) {
                if (r + j < end) {
                    int idx = r + j - beg;
                    if (idx < CAPD) exsh[wv][idx * 4 + h] = ex[j];
                    else            EX2[(size_t)(r + j) * 4 + h] = ex[j];
                }
            }
        }
#pragma unroll
        for (int j = 0; j < 8; ++j) {
            den  += ex[j];
            acc0 += ex[j] * lo16(u[j]);
            acc1 += ex[j] * hi16(u[j]);
        }
    }
    float invn = 1.f / fmaxf(den, 1e-30f);
    float v0 = acc0 * invn + bo[c0], v1 = acc1 * invn + bo[c0 + 1];
    if (relu) { v0 = fmaxf(v0, 0.f); v1 = fmaxf(v1, 0.f); }
    __hip_bfloat16 h0 = f2b(v0), h1 = f2b(v1);
    ushort2 st;
    st.x = *(unsigned short*)&h0;
    st.y = *(unsigned short*)&h1;
    ((ushort2*)(hout + (size_t)n * 128))[lane] = st;
    // alpha outputs: 16 edges in parallel, lane (h,l16) handles (r0+l16, h)
    int isF32 = *flag;
    for (int r0 = beg; r0 < end; r0 += 16) {
        int rr = r0 + l16;
        if (rr < end) {
            int idx = rr - beg;
            float ex = (idx < CAPD) ? exsh[wv][idx * 4 + h]
                                    : EX2[(size_t)rr * 4 + h];
            int e = eidx[rr];
            store_out(alpha_out, aoff + (size_t)e * 4 + h, ex * invn, isF32);
        }
    }
}

extern "C" void kernel_launch(void* const* d_in, const int* in_sizes, int n_in,
                              void* d_out, int out_size, void* d_ws, size_t ws_size,
                              hipStream_t stream) {
    const int* ei = (const int*)d_in[1];
    const int N  = in_sizes[0] / 16;
    const int E  = in_sizes[1] / 2;
    const int ET = E + N;
    const int NB = (N + 255) / 256;          // scan blocks

    // ---------------- workspace carve ------------------------------------
    float* P = (float*)d_ws;
    float* encW = P; P += 2048;  float* encb = P; P += 128;
    float* b1l  = P; P += 128;   float* b1r  = P; P += 128;
    float* att1 = P; P += 128;   float* bo1  = P; P += 128;
    float* b2l  = P; P += 128;   float* b2r  = P; P += 128;
    float* att2 = P; P += 128;   float* bo2  = P; P += 128;
    float* mb1  = P; P += 128;   float* mW2  = P; P += 128;
    float* mb2  = P; P += 4;
    int*  FLAG  = (int*)P; P += 4;
    int*  CNT   = (int*)P; P += N;
    int*  RS    = (int*)P; P += N + 1;
    int*  CUR   = (int*)P; P += N;
    int*  BSUM  = (int*)P; P += NB;
    int*  EIDX  = (int*)P; P += ET;
    int*  SRC   = (int*)P; P += ET;
    float* EX2  = P; P += (size_t)ET * 4;
    P = (float*)(((uintptr_t)P + 15) & ~(uintptr_t)15);   // 16B align
    __hip_bfloat16* W1Lt = (__hip_bfloat16*)P;            // 5 x 128*128 bf16
    __hip_bfloat16* W1Rt = W1Lt + 16384;
    __hip_bfloat16* W2Lt = W1Rt + 16384;
    __hip_bfloat16* W2Rt = W2Lt + 16384;
    __hip_bfloat16* MW1t = W2Rt + 16384;
    __hip_bfloat16* Hb   = MW1t + 16384;                  // N*128 bf16
    __hip_bfloat16* XL   = Hb + (size_t)N * 128;
    __hip_bfloat16* XR   = XL + (size_t)N * 128;

    // ---------------- fused param conversion (local dtype detect) ---------
    CvtTab tab;
    const int srcIdx[NCVT] = {4, 5, 7, 9, 10, 11, 13, 15, 16, 17, 19, 20, 21};
    float* dsts[NCVT] = {encW, encb, b1l, b1r, att1, bo1, b2l, b2r, att2, bo2, mb1, mW2, mb2};
    const int ns[NCVT] = {2048, 128, 128, 128, 128, 128, 128, 128, 128, 128, 128, 128, 1};
    int tot = 0;
    for (int i = 0; i < NCVT; ++i) {
        tab.src[i] = d_in[srcIdx[i]];
        tab.dst[i] = dsts[i];
        tab.n[i] = ns[i];
        tot += ns[i];
    }
    tab.total = tot;
    const unsigned short* det = (const unsigned short*)d_in[4];  // enc_W raw
    k_cvt_all<<<(tot + 255) / 256, 256, 0, stream>>>(tab, det, FLAG);

    WtTab wt;
    wt.src[0] = d_in[6];  wt.dst[0] = W1Lt;
    wt.src[1] = d_in[8];  wt.dst[1] = W1Rt;
    wt.src[2] = d_in[12]; wt.dst[2] = W2Lt;
    wt.src[3] = d_in[14]; wt.dst[3] = W2Rt;
    wt.src[4] = d_in[18]; wt.dst[4] = MW1t;
    k_cvtWt_all<<<640, 128, 0, stream>>>(wt, det);

    // ---------------- CSR by dst (parallel scan) --------------------------
    const int etGrid = (ET + 255) / 256;
    k_zero<<<NB, 256, 0, stream>>>(CNT, N);
    k_hist<<<etGrid, 256, 0, stream>>>(ei, E, N, CNT);
    k_scanA<<<NB, 256, 0, stream>>>(CNT, N, RS, BSUM);
    k_scanB<<<1, 1024, 0, stream>>>(BSUM, NB, RS, N);
    k_scanC<<<NB, 256, 0, stream>>>(RS, CUR, BSUM, N);
    k_fill<<<etGrid, 256, 0, stream>>>(ei, E, N, CUR, EIDX, SRC);

    const size_t a1_off = (size_t)N;
    const size_t a2_off = (size_t)N + (size_t)ET * 4;
    const int gGrid = (N + 63) / 64;
    const int fGrid = (N + 3) / 4;

    // ---- GAT layer 1 (encoder fused into the GEMM) ----
    k_gemm2enc_mfma<<<gGrid, 256, 0, stream>>>(d_in[0], encW, encb, FLAG,
                                               W1Lt, b1l, W1Rt, b1r, N, XL, XR);
    k_gat_fused<<<fGrid, 256, 0, stream>>>(XL, XR, RS, SRC, EIDX, N, att1, bo1, 1,
                                           EX2, d_out, a1_off, FLAG, Hb);

    // ---- GAT layer 2 ----
    k_gemm2_mfma<<<gGrid, 256, 0, stream>>>(Hb, W2Lt, b2l, W2Rt, b2r, N, XL, XR);
    k_gat_fused<<<fGrid, 256, 0, stream>>>(XL, XR, RS, SRC, EIDX, N, att2, bo2, 0,
                                           EX2, d_out, a2_off, FLAG, Hb);

    k_mlp_mfma<<<gGrid, 256, 0, stream>>>(Hb, MW1t, mb1, mW2, mb2, N, d_out, FLAG);
}